// Round 11
// baseline (338.317 us; speedup 1.0000x reference)
//
#include <hip/hip_runtime.h>
#include <hip/hip_bf16.h>
#include <math.h>

#define NN 10000
#define NE 100000
#define NB 32

typedef __attribute__((ext_vector_type(8))) short short8;
typedef __attribute__((ext_vector_type(4))) float f32x4;
typedef __attribute__((ext_vector_type(2))) float f32x2;
typedef _Float16 h2 __attribute__((ext_vector_type(2)));

union H8 { short8 s; h2 h[4]; };
union HU { _Float16 h; ushort u; };

__device__ inline ushort f2b(float f) {
  union { float f; unsigned u; } a; a.f = f;
  unsigned r = a.u + 0x7fff + ((a.u >> 16) & 1);
  return (ushort)(r >> 16);
}
__device__ inline float bf2f(ushort u) {
  union { unsigned u; float f; } a; a.u = ((unsigned)u) << 16;
  return a.f;
}
__device__ inline ushort f2h(float f) { HU x; x.h = (_Float16)f; return x.u; }
__device__ inline float h2f(ushort u) { HU x; x.u = u; return (float)x.h; }

// ---- fp8 e4m3 encode/decode (HW on gfx950, SW fallback) ----
__device__ inline float e4m3_sw(unsigned b) {
  unsigned s = b & 0x80, e = (b >> 3) & 15, m = b & 7;
  float v = (e == 0) ? (float)m * (1.f / 512.f) : ldexpf((float)(8 + m), (int)e - 10);
  return s ? -v : v;
}
__device__ inline unsigned f2e4m3_sw(float f) {
  unsigned s = (__float_as_uint(f) >> 24) & 0x80;
  float a = fabsf(f);
  if (a < 0.0009765625f) return s;
  if (a >= 448.f) return s | 0x7e;
  if (a < 0.015625f) {
    int q = (int)rintf(a * 512.f);
    return s | (unsigned)q;
  }
  int e2; frexpf(a, &e2);
  int sh = e2 - 4;
  int M = (int)rintf(ldexpf(a, -sh));
  if (M >= 16) { M >>= 1; sh++; }
  int E = sh + 10;
  if (E > 15) return s | 0x7e;
  return s | (unsigned)((E << 3) | (M - 8));
}

#if defined(__has_builtin)
#if __has_builtin(__builtin_amdgcn_cvt_pk_f32_fp8) && __has_builtin(__builtin_amdgcn_cvt_pk_fp8_f32)
#define HW_FP8 1
#endif
#endif

#ifdef HW_FP8
template <bool HI>
__device__ inline f32x2 dec2(unsigned w) {
  return __builtin_amdgcn_cvt_pk_f32_fp8((int)w, HI);
}
template <bool HI>
__device__ inline unsigned enc2(float a, float b, unsigned old) {
  return (unsigned)__builtin_amdgcn_cvt_pk_fp8_f32(a, b, (int)old, HI);
}
#else
template <bool HI>
__device__ inline f32x2 dec2(unsigned w) {
  unsigned x = HI ? (w >> 16) : (w & 0xffff);
  f32x2 r; r[0] = e4m3_sw(x & 0xff); r[1] = e4m3_sw((x >> 8) & 0xff);
  return r;
}
template <bool HI>
__device__ inline unsigned enc2(float a, float b, unsigned old) {
  unsigned pk = f2e4m3_sw(a) | (f2e4m3_sw(b) << 8);
  return HI ? ((old & 0xffffu) | (pk << 16)) : ((old & 0xffff0000u) | pk);
}
#endif

#if defined(__has_builtin)
#if __has_builtin(__builtin_amdgcn_fdot2)
#define FDOT2(a, b, c) __builtin_amdgcn_fdot2((a), (b), (c), false)
#endif
#endif
#ifndef FDOT2
#define FDOT2(a, b, c) ((c) + (float)(a)[0] * (float)(b)[0] + (float)(a)[1] * (float)(b)[1])
#endif

#define GLDS(g, l)                                                        \
  __builtin_amdgcn_global_load_lds(                                       \
      (const __attribute__((address_space(1))) unsigned*)(g),             \
      (__attribute__((address_space(3))) unsigned*)(l), 16, 0, 0)

// ------- qkvt GEMM: A[M,128](bf16) @ Bt[3584,128]^T + bias ->
//   cols [0,1024) f16->qt, [1024,3072) fp8->kv8, [3072,3584) f16->qt(+1024-2048)
//   B fragments read DIRECT from global (L2-hot, reused by 79 row-blocks); only A in LDS.
__global__ __launch_bounds__(256) void k_gemm_qkvt(
    const ushort* __restrict__ Abf, const ushort* __restrict__ Bt,
    const float* __restrict__ bias, ushort* __restrict__ qt,
    unsigned char* __restrict__ kv8, int M) {
  __shared__ ushort As[128 * 128];
  const int tid = threadIdx.x;
  const int l = tid & 63, w = tid >> 6;
  const int wm = w & 1, wn = w >> 1;
  const int row0 = blockIdx.y * 128, col0 = blockIdx.x * 128;
#pragma unroll
  for (int i = 0; i < 8; ++i) {
    int idx = i * 256 + tid;
    int r = idx >> 4, cb = (idx & 15) << 4;
    int scb = cb ^ ((r & 7) << 4);   // pre-swizzled source, linear LDS dest
    GLDS((const char*)Abf + (size_t)(row0 + r) * 256 + scb, (char*)As + idx * 16);
  }
  __syncthreads();
  f32x4 acc[4][4] = {};
#pragma unroll
  for (int kk = 0; kk < 4; ++kk) {
    short8 af[4], bf[4];
#pragma unroll
    for (int fm = 0; fm < 4; ++fm) {
      int r = wm * 64 + fm * 16 + (l & 15);
      int cb = (kk * 64 + ((l >> 4) << 4)) ^ ((r & 7) << 4);
      af[fm] = *(const short8*)((const char*)As + r * 256 + cb);
    }
#pragma unroll
    for (int fn = 0; fn < 4; ++fn) {
      int r = wn * 64 + fn * 16 + (l & 15);
      bf[fn] = *(const short8*)((const char*)Bt + (size_t)(col0 + r) * 256 + kk * 64 + ((l >> 4) << 4));
    }
#pragma unroll
    for (int fm = 0; fm < 4; ++fm)
#pragma unroll
      for (int fn = 0; fn < 4; ++fn)
        acc[fm][fn] = __builtin_amdgcn_mfma_f32_16x16x32_bf16(af[fm], bf[fn], acc[fm][fn], 0, 0, 0);
  }
  // stage acc (f16) into As, swizzled
  __syncthreads();
#pragma unroll
  for (int fm = 0; fm < 4; ++fm) {
    int rloc = wm * 64 + fm * 16 + ((l >> 4) << 2);
#pragma unroll
    for (int fn = 0; fn < 4; ++fn) {
      int cbyte = (wn * 64 + fn * 16 + (l & 15)) * 2;
#pragma unroll
      for (int b = 0; b < 4; ++b) {
        int r = rloc + b;
        *(ushort*)((char*)As + r * 256 + (cbyte ^ ((r & 7) << 4))) = f2h(acc[fm][fn][b]);
      }
    }
  }
  __syncthreads();
  const bool isf16 = (col0 < 1024) || (col0 >= 3072);
#pragma unroll
  for (int it = 0; it < 8; ++it) {
    int idx = it * 256 + tid;
    int r = idx >> 4, cb16 = (idx & 15) << 4;
    int gr = row0 + r;
    if (gr >= M) continue;
    short8 v = *(const short8*)((const char*)As + r * 256 + (cb16 ^ ((r & 7) << 4)));
    int co = cb16 >> 1;  // col offset within 128, multiple of 8
    if (isf16) {
      int qc0 = ((col0 < 1024) ? col0 : (col0 - 2048)) + co;
      short8 o;
#pragma unroll
      for (int j = 0; j < 8; ++j) o[j] = (short)f2h(h2f((ushort)v[j]) + bias[col0 + co + j]);
      *(short8*)(qt + (size_t)gr * 1536 + qc0) = o;
    } else {
      float f[8];
#pragma unroll
      for (int j = 0; j < 8; ++j) f[j] = h2f((ushort)v[j]) + bias[col0 + co + j];
      unsigned w0 = 0, w1 = 0;
      w0 = enc2<false>(f[0], f[1], w0);
      w0 = enc2<true>(f[2], f[3], w0);
      w1 = enc2<false>(f[4], f[5], w1);
      w1 = enc2<true>(f[6], f[7], w1);
      uint2 st; st.x = w0; st.y = w1;
      *(uint2*)(kv8 + (size_t)gr * 2048 + (col0 - 1024) + co) = st;
    }
  }
}

// ------- fused output GEMM: hbuf[M,128] = s_b[M,512]@W2t^T + x[M,128]@Wsk^T + bsk + mbuf ---
// B fragments direct from global (L2-hot); only A staged in LDS.
__global__ __launch_bounds__(256) void k_gemm_out(
    const ushort* __restrict__ s_b, const ushort* __restrict__ xin,
    const ushort* __restrict__ W2t, const ushort* __restrict__ Wsk,
    const float* __restrict__ bsk, const float* __restrict__ mbuf,
    float* __restrict__ Cf, int M) {
  __shared__ ushort As[128 * 128];
  const int tid = threadIdx.x;
  const int l = tid & 63, w = tid >> 6;
  const int wm = w & 1, wn = w >> 1;
  const int row0 = blockIdx.y * 128;
  f32x4 acc[4][4] = {};
  for (int kt = 0; kt < 5; ++kt) {
    if (kt) __syncthreads();
    const char* Ab; const char* Bb; size_t arb, brb; int ko;
    if (kt < 4) { Ab = (const char*)s_b; arb = 1024; Bb = (const char*)W2t; brb = 1024; ko = kt * 256; }
    else        { Ab = (const char*)xin; arb = 256;  Bb = (const char*)Wsk; brb = 256;  ko = 0; }
#pragma unroll
    for (int i = 0; i < 8; ++i) {
      int idx = i * 256 + tid;
      int r = idx >> 4, cb = (idx & 15) << 4;
      int scb = cb ^ ((r & 7) << 4);
      GLDS(Ab + (size_t)(row0 + r) * arb + ko + scb, (char*)As + idx * 16);
    }
    __syncthreads();
#pragma unroll
    for (int kk = 0; kk < 4; ++kk) {
      short8 af[4], bf[4];
#pragma unroll
      for (int fm = 0; fm < 4; ++fm) {
        int r = wm * 64 + fm * 16 + (l & 15);
        int cb = (kk * 64 + ((l >> 4) << 4)) ^ ((r & 7) << 4);
        af[fm] = *(const short8*)((const char*)As + r * 256 + cb);
      }
#pragma unroll
      for (int fn = 0; fn < 4; ++fn) {
        int r = wn * 64 + fn * 16 + (l & 15);
        bf[fn] = *(const short8*)(Bb + (size_t)r * brb + ko + kk * 64 + ((l >> 4) << 4));
      }
#pragma unroll
      for (int fm = 0; fm < 4; ++fm)
#pragma unroll
        for (int fn = 0; fn < 4; ++fn)
          acc[fm][fn] = __builtin_amdgcn_mfma_f32_16x16x32_bf16(af[fm], bf[fn], acc[fm][fn], 0, 0, 0);
    }
  }
#pragma unroll
  for (int fm = 0; fm < 4; ++fm) {
    int row = row0 + wm * 64 + fm * 16 + ((l >> 4) << 2);
#pragma unroll
    for (int fn = 0; fn < 4; ++fn) {
      int col = wn * 64 + fn * 16 + (l & 15);
      if (col >= 128) continue;
      float bb = bsk[col];
#pragma unroll
      for (int b = 0; b < 4; ++b) {
        int rr = row + b;
        if (rr >= M) continue;
        Cf[(size_t)rr * 128 + col] = acc[fm][fn][b] + bb + mbuf[(size_t)rr * 128 + col];
      }
    }
  }
}

// ---------------- weight prep ----------------
struct WtPrep { const float* W[8]; ushort* O[8]; int Nc[8]; };
__global__ void k_wt_all(WtPrep P) {
  const int z = blockIdx.z;
  const int Nc = P.Nc[z];
  if ((int)blockIdx.x * 32 >= Nc) return;
  const float* __restrict__ W = P.W[z];
  ushort* __restrict__ Wt = P.O[z];
  __shared__ float tile[32][33];
  const int t = threadIdx.x, lx = t & 31, ly = t >> 5;
  const int bx = blockIdx.x, by = blockIdx.y;
#pragma unroll
  for (int i = 0; i < 4; ++i)
    tile[ly + i * 8][lx] = W[(by * 32 + ly + i * 8) * Nc + bx * 32 + lx];
  __syncthreads();
#pragma unroll
  for (int i = 0; i < 4; ++i)
    Wt[(size_t)(bx * 32 + ly + i * 8) * 128 + by * 32 + lx] = f2b(tile[lx][ly + i * 8]);
}

struct PrepPtrs {
  const float* Wq[2]; const float* We[2]; ushort* Mt[2];
  const float* bq[2]; const float* bk[2]; const float* bv[2];
  ushort* W2t[2]; float* biasAll[2];
};

// Mt[(h*64+d)*128 + p] = bf16( sum_c Wq[p,h*128+c] * We[d,h*128+c] );  grid (64, 2)
__global__ __launch_bounds__(256) void k_mwt(PrepPtrs P) {
  const int L = blockIdx.y;
  const float* __restrict__ Wq = P.Wq[L];
  const float* __restrict__ We = P.We[L];
  ushort* __restrict__ Mt = P.Mt[L];
  const int h = blockIdx.x >> 3, pt = blockIdx.x & 7;
  const int t = threadIdx.x;
  __shared__ float Wes[64][129];
  __shared__ float Wqs[16][129];
#pragma unroll
  for (int i = 0; i < 32; ++i) {
    int idx = i * 256 + t;
    Wes[idx >> 7][idx & 127] = We[(idx >> 7) * 1024 + h * 128 + (idx & 127)];
  }
#pragma unroll
  for (int i = 0; i < 8; ++i) {
    int idx = i * 256 + t;
    Wqs[idx >> 7][idx & 127] = Wq[(pt * 16 + (idx >> 7)) * 1024 + h * 128 + (idx & 127)];
  }
  __syncthreads();
#pragma unroll
  for (int i = 0; i < 4; ++i) {
    int o = i * 256 + t;
    int d = o & 63, p = o >> 6;
    float s = 0.f;
#pragma unroll 8
    for (int c = 0; c < 128; ++c) s += Wqs[p][c] * Wes[d][c];
    Mt[(size_t)(h * 64 + d) * 128 + pt * 16 + p] = f2b(s);
  }
}

// W2t[c*512 + h*64+d] = bf16( We[d,h*128+c] / 8 );  grid (256, 2)
__global__ void k_w2t(PrepPtrs P) {
  const int L = blockIdx.y;
  int o = blockIdx.x * 256 + threadIdx.x;
  if (o < 128 * 512) {
    int c = o >> 9, hd = o & 511;
    int hh = hd >> 6, d = hd & 63;
    P.W2t[L][o] = f2b(P.We[L][d * 1024 + hh * 128 + c] * 0.125f);
  }
}

// biasAll[0..3071] = cat(bq,bk,bv); biasAll[3072+h*64+d] = bq·We;  grid (14, 2)
__global__ void k_bias_all(PrepPtrs P) {
  const int L = blockIdx.y;
  int o = blockIdx.x * 256 + threadIdx.x;
  if (o < 1024) P.biasAll[L][o] = P.bq[L][o];
  else if (o < 2048) P.biasAll[L][o] = P.bk[L][o - 1024];
  else if (o < 3072) P.biasAll[L][o] = P.bv[L][o - 2048];
  else if (o < 3584) {
    int hd = o - 3072;
    int h = hd >> 6, d = hd & 63;
    float s = 0.f;
    for (int c = 0; c < 128; ++c) s += P.bq[L][h * 128 + c] * P.We[L][d * 1024 + h * 128 + c];
    P.biasAll[L][o] = s;
  }
}

__global__ void k_cvt(const float* __restrict__ in, ushort* __restrict__ out, int n4) {
  int i = blockIdx.x * 256 + threadIdx.x;
  if (i < n4) {
    float4 v = *(const float4*)(in + i * 4);
    ushort4 o;
    o.x = f2b(v.x); o.y = f2b(v.y); o.z = f2b(v.z); o.w = f2b(v.w);
    *(ushort4*)(out + i * 4) = o;
  }
}

// ---------------- CSR build over dst ----------------
__global__ void k_histo(const int* __restrict__ dst, int* __restrict__ cnt) {
  int e = blockIdx.x * 256 + threadIdx.x;
  if (e < NE) atomicAdd(&cnt[dst[e]], 1);
}

__global__ __launch_bounds__(256) void k_scan(const int* __restrict__ cnt,
                                              int* __restrict__ ptr) {
  __shared__ int tsum[256];
  const int t = threadIdx.x;
  const int base = t * 40;
  int s = 0;
  for (int i = 0; i < 40; ++i) { int idx = base + i; if (idx < NN) s += cnt[idx]; }
  tsum[t] = s;
  __syncthreads();
  for (int off = 1; off < 256; off <<= 1) {
    int v = (t >= off) ? tsum[t - off] : 0;
    __syncthreads();
    tsum[t] += v;
    __syncthreads();
  }
  int run = (t == 0) ? 0 : tsum[t - 1];
  for (int i = 0; i < 40; ++i) {
    int idx = base + i;
    if (idx < NN) { ptr[idx] = run; run += cnt[idx]; }
  }
  if (t == 255) ptr[NN] = tsum[255];
}

// countdown scatter: cnt[d] holds degree after histo; no second memset needed
__global__ void k_scatter(const int* __restrict__ dst, const int* __restrict__ ptr,
                          int* __restrict__ cnt, int* __restrict__ eid) {
  int e = blockIdx.x * 256 + threadIdx.x;
  if (e < NE) {
    int d = dst[e];
    int pos = ptr[d] + atomicSub(&cnt[d], 1) - 1;
    eid[pos] = e;
  }
}

// LPT order: counting sort of nodes by degree, DESCENDING. Single block.
__global__ __launch_bounds__(256) void k_sortdeg(const int* __restrict__ ptr,
                                                 int* __restrict__ order) {
  __shared__ int hist[256];
  __shared__ int offs[256];
  __shared__ int fill[256];
  __shared__ int sc[256];
  const int t = threadIdx.x;
  hist[t] = 0;
  __syncthreads();
  for (int n = t; n < NN; n += 256) {
    int d = min(ptr[n + 1] - ptr[n], 255);
    atomicAdd(&hist[d], 1);
  }
  __syncthreads();
  const int rd = 255 - t;
  int v = hist[rd];
  sc[t] = v;
  __syncthreads();
  for (int off = 1; off < 256; off <<= 1) {
    int u = (t >= off) ? sc[t - off] : 0;
    __syncthreads();
    sc[t] += u;
    __syncthreads();
  }
  offs[rd] = sc[t] - v;   // sum of counts of all higher degrees
  fill[rd] = 0;
  __syncthreads();
  for (int n = t; n < NN; n += 256) {
    int d = min(ptr[n + 1] - ptr[n], 255);
    int pos = offs[d] + atomicAdd(&fill[d], 1);
    order[pos] = n;
  }
}

// permute attr (f32->f16) and src into CSR slot order
__global__ void k_permattr(const int* __restrict__ eid, const int* __restrict__ src,
                           const float* __restrict__ attr, int* __restrict__ src_p,
                           ushort* __restrict__ attr_p) {
  int i = blockIdx.x * 256 + threadIdx.x;
  if (i >= NE * 16) return;
  int idx = i >> 4, part = i & 15;
  int e = eid[idx];
  if (part == 0) src_p[idx] = src[e];
  float4 v = *(const float4*)(attr + (size_t)e * 64 + part * 4);
  ushort4 o;
  o.x = f2h(v.x); o.y = f2h(v.y); o.z = f2h(v.z); o.w = f2h(v.w);
  *(ushort4*)(attr_p + (size_t)idx * 64 + part * 4) = o;
}

// ---------------- batch boundaries (batch is sorted) ----------------
__global__ void k_bptr(const int* __restrict__ batch, int* __restrict__ bptr) {
  int b = threadIdx.x;
  if (b > NB) return;
  int lo = 0, hi = NN;
  while (lo < hi) { int mid = (lo + hi) >> 1; if (batch[mid] < b) lo = mid + 1; else hi = mid; }
  bptr[b] = lo;
}

// ---------------- fused attention: 4 independent waves/block, 2-deep edge pipeline ----
// qt row: [q(1024) | t(512)] f16. kv8 row: [k(1024) | v(1024)] fp8 e4m3.
// lane l owns channels l*16..l*16+15 (head h=l>>3, sub i=l&7). No __syncthreads.
// NOTE: no min-waves clamp (R9: forcing 8 waves/EU squeezed VGPRs 52->32, spilled).
__global__ __launch_bounds__(256) void k_fused(
    const ushort* __restrict__ qt, const unsigned char* __restrict__ kv8,
    const ushort* __restrict__ attr_p, const int* __restrict__ src_p,
    const int* __restrict__ ptr, const int* __restrict__ order,
    float* __restrict__ mbuf, ushort* __restrict__ s_b) {
  const int slot = blockIdx.x * 4 + (threadIdx.x >> 6);
  if (slot >= NN) return;
  const int n = order[slot];
  const int l = threadIdx.x & 63;
  const int i = l & 7;
  float qf[16];
  {
    H8 q0, q1;
    const ushort* qr = qt + (size_t)n * 1536 + l * 16;
    q0.s = *(const short8*)qr;
    q1.s = *(const short8*)(qr + 8);
#pragma unroll
    for (int j = 0; j < 8; ++j) { qf[j] = h2f((ushort)q0.s[j]); qf[8 + j] = h2f((ushort)q1.s[j]); }
  }
  H8 tv;
  tv.s = *(const short8*)(qt + (size_t)n * 1536 + 1024 + l * 8);
  const int beg = ptr[n], end = ptr[n + 1];
  float m = -1e30f, den = 0.f;
  float acc[16] = {};
  float sa[8] = {};
  // 2-deep pipeline: E0 = edge idx (loaded), E1 = edge idx+1 (in flight), sC = src of idx+2
  uint4 k0, v0, k1, v1; H8 a0, a1;
  int sC = 0;
  if (beg < end) {
    const int last = end - 1;
    int sA = src_p[beg];
    const unsigned char* kr = kv8 + (size_t)sA * 2048 + l * 16;
    k0 = *(const uint4*)kr;
    v0 = *(const uint4*)(kr + 1024);
    a0.s = *(const short8*)(attr_p + (size_t)beg * 64 + i * 8);
    int i1 = min(beg + 1, last);
    int sB = src_p[i1];
    kr = kv8 + (size_t)sB * 2048 + l * 16;
    k1 = *(const uint4*)kr;
    v1 = *(const uint4*)(kr + 1024);
    a1.s = *(const short8*)(attr_p + (size_t)i1 * 64 + i * 8);
    sC = src_p[min(beg + 2, last)];
  }
  const int last = end - 1;
  for (int idx = beg; idx < end; ++idx) {
    uint4 ckw = k0, cvw = v0; H8 cav = a0;
    k0 = k1; v0 = v1; a0 = a1;
    // issue loads for edge idx+2 using pre-loaded sC
    int i2 = min(idx + 2, last);
    const unsigned char* kr = kv8 + (size_t)sC * 2048 + l * 16;
    k1 = *(const uint4*)kr;
    v1 = *(const uint4*)(kr + 1024);
    a1.s = *(const short8*)(attr_p + (size_t)i2 * 64 + i * 8);
    sC = src_p[min(idx + 3, last)];  // src for next iteration's issue
    float p = 0.f;
    {
      const unsigned* kws = (const unsigned*)&ckw;
#pragma unroll
      for (int j = 0; j < 4; ++j) {
        f32x2 lo = dec2<false>(kws[j]), hi = dec2<true>(kws[j]);
        p += qf[4 * j] * lo[0] + qf[4 * j + 1] * lo[1]
           + qf[4 * j + 2] * hi[0] + qf[4 * j + 3] * hi[1];
      }
    }
#pragma unroll
    for (int j = 0; j < 4; ++j) p = FDOT2(tv.h[j], cav.h[j], p);
    p += __shfl_xor(p, 1, 64);
    p += __shfl_xor(p, 2, 64);
    p += __shfl_xor(p, 4, 64);
    p *= 0.12751593061420927f;  // (1/sqrt(128)) * log2(e) -> exp2 domain
    float mn = fmaxf(m, p);
    float r = exp2f(m - mn);
    float ex = exp2f(p - mn);
    den = den * r + ex;
    {
      const unsigned* vws = (const unsigned*)&cvw;
#pragma unroll
      for (int j = 0; j < 4; ++j) {
        f32x2 lo = dec2<false>(vws[j]), hi = dec2<true>(vws[j]);
        acc[4 * j]     = acc[4 * j]     * r + ex * lo[0];
        acc[4 * j + 1] = acc[4 * j + 1] * r + ex * lo[1];
        acc[4 * j + 2] = acc[4 * j + 2] * r + ex * hi[0];
        acc[4 * j + 3] = acc[4 * j + 3] * r + ex * hi[1];
      }
    }
#pragma unroll
    for (int j = 0; j < 4; ++j) {
      sa[2 * j]     = sa[2 * j]     * r + ex * (float)cav.h[j][0];
      sa[2 * j + 1] = sa[2 * j + 1] * r + ex * (float)cav.h[j][1];
    }
    m = mn;
  }
  const float invd = den > 0.f ? 1.f / den : 0.f;
  short8 sb;
#pragma unroll
  for (int j = 0; j < 8; ++j) sb[j] = (short)f2b(sa[j] * invd);
  *(short8*)(s_b + (size_t)n * 512 + l * 8) = sb;
#pragma unroll
  for (int j = 0; j < 16; ++j) {
    float a = acc[j] * invd;
    a += __shfl_xor(a, 8, 64);
    a += __shfl_xor(a, 16, 64);
    a += __shfl_xor(a, 32, 64);
    acc[j] = a;
  }
  if (l < 8) {  // h==0 lanes, i==l
    float* mb = mbuf + (size_t)n * 128 + l * 16;
#pragma unroll
    for (int j = 0; j < 16; j += 4) {
      float4 o = make_float4(acc[j] * 0.125f, acc[j + 1] * 0.125f,
                             acc[j + 2] * 0.125f, acc[j + 3] * 0.125f);
      *(float4*)(mb + j) = o;
    }
  }
}

// ---------------- GraphNorm: atomic-free partials, finalize in apply ----
// part layout: gs[chunk][b][c] then gs2[chunk][b][c], chunk in 0..3
__global__ __launch_bounds__(256) void k_gn_partial(
    const float* __restrict__ x, const int* __restrict__ bptr,
    float* __restrict__ part) {
  const int b = blockIdx.x >> 2, chunk = blockIdx.x & 3;
  const int t = threadIdx.x;
  const int c = t & 127, half = t >> 7;
  const int beg = bptr[b], end = bptr[b + 1];
  float s = 0.f, s2 = 0.f;
  for (int n = beg + chunk * 2 + half; n < end; n += 8) {
    float v = x[(size_t)n * 128 + c];
    s += v; s2 += v * v;
  }
  __shared__ float r1[256];
  __shared__ float r2[256];
  r1[t] = s; r2[t] = s2;
  __syncthreads();
  if (half == 0) {
    part[((size_t)chunk * NB + b) * 128 + c] = r1[c] + r1[c + 128];
    part[4 * NB * 128 + ((size_t)chunk * NB + b) * 128 + c] = r2[c] + r2[c + 128];
  }
}

__global__ void k_gn_apply(const float* __restrict__ x, const int* __restrict__ batch,
                           const int* __restrict__ bptr, const float* __restrict__ part,
                           const float* __restrict__ ms, const float* __restrict__ wgt,
                           const float* __restrict__ gnb,
                           float* __restrict__ fout, ushort* __restrict__ bout) {
  int i = blockIdx.x * 256 + threadIdx.x;
  int n = i >> 7, c = i & 127;
  int b = batch[n];
  float S = 0.f, S2 = 0.f;
#pragma unroll
  for (int ch = 0; ch < 4; ++ch) {
    S  += part[((size_t)ch * NB + b) * 128 + c];
    S2 += part[4 * NB * 128 + ((size_t)ch * NB + b) * 128 + c];
  }
  float cnt = fmaxf((float)(bptr[b + 1] - bptr[b]), 1.f);
  float mean = S / cnt;
  float mm = mean * ms[c];
  float var = S2 / cnt - 2.f * mm * mean + mm * mm;
  float o = (x[i] - mm) * rsqrtf(var + 1e-5f) * wgt[c] + gnb[c];
  o = o > 0.f ? o : 0.01f * o;
  if (fout) fout[i] = o;
  if (bout) bout[i] = f2b(o);
}

extern "C" void kernel_launch(void* const* d_in, const int* in_sizes, int n_in,
                              void* d_out, int out_size, void* d_ws, size_t ws_size,
                              hipStream_t stream) {
  const float* x     = (const float*)d_in[0];
  const int*   index = (const int*)d_in[1];
  const float* attr  = (const float*)d_in[2];
  const int*   batch = (const int*)d_in[3];
  const int* srcArr = index;
  const int* dstArr = index + NE;

  char* p = (char*)d_ws;
  auto take = [&](size_t bytes) {
    char* r = p;
    p += (bytes + 255) & ~(size_t)255;
    return (void*)r;
  };
  ushort* qt_b   = (ushort*)take((size_t)NN * 1536 * 2);   // f16 [q|t]
  unsigned char* kv8 = (unsigned char*)take((size_t)NN * 2048);  // fp8 [k|v]
  ushort* s_b    = (ushort*)take((size_t)NN * 512 * 2);    // bf16
  float*  mbuf   = (float*)take((size_t)NN * 128 * 4);
  float*  hbuf   = (float*)take((size_t)NN * 128 * 4);
  ushort* xb     = (ushort*)take((size_t)NN * 128 * 2);    // bf16
  ushort* x2b    = (ushort*)take((size_t)NN * 128 * 2);    // bf16
  ushort* attr_p = (ushort*)take((size_t)NE * 64 * 2);     // f16, CSR order
  int*    src_p  = (int*)take((size_t)NE * 4);
  float*  part   = (float*)take((size_t)4 * NB * 128 * 2 * 4);
  int* csr_ptr   = (int*)take((size_t)(NN + 1) * 4);
  int* csr_cnt   = (int*)take((size_t)NN * 4);
  int* csr_eid   = (int*)take((size_t)NE * 4);
  int* nodeorder = (int*)take((size_t)NN * 4);
  int* bptrd     = (int*)take((size_t)(NB + 1) * 4);
  ushort* WtAll[2]; ushort* Wtsk[2]; ushort* W2t[2];
  float* biasAll[2];
  for (int L = 0; L < 2; ++L) {
    WtAll[L]   = (ushort*)take((size_t)3584 * 128 * 2);  // [q|k|v|t] rows, bf16
    Wtsk[L]    = (ushort*)take((size_t)128 * 128 * 2);
    W2t[L]     = (ushort*)take((size_t)128 * 512 * 2);
    biasAll[L] = (float*)take((size_t)3584 * 4);
  }

  // ---- CSR over dst + LPT order + batch boundaries + conversions ----
  hipMemsetAsync(csr_cnt, 0, NN * 4, stream);
  k_histo<<<(NE + 255) / 256, 256, 0, stream>>>(dstArr, csr_cnt);
  k_scan<<<1, 256, 0, stream>>>(csr_cnt, csr_ptr);
  k_scatter<<<(NE + 255) / 256, 256, 0, stream>>>(dstArr, csr_ptr, csr_cnt, csr_eid);
  k_sortdeg<<<1, 256, 0, stream>>>(csr_ptr, nodeorder);
  k_permattr<<<(NE * 16 + 255) / 256, 256, 0, stream>>>(csr_eid, srcArr, attr, src_p, attr_p);
  k_bptr<<<1, 64, 0, stream>>>(batch, bptrd);
  k_cvt<<<(NN * 128 / 4 + 255) / 256, 256, 0, stream>>>(x, xb, NN * 128 / 4);

  // ---- weight prep (all matrices, both layers) ----
  WtPrep WP;
  PrepPtrs PP;
  for (int L = 0; L < 2; ++L) {
    const float* Wq  = (const float*)d_in[4 + L * 12 + 0];
    const float* bq  = (const float*)d_in[4 + L * 12 + 1];
    const float* Wk  = (const float*)d_in[4 + L * 12 + 2];
    const float* bk  = (const float*)d_in[4 + L * 12 + 3];
    const float* Wv  = (const float*)d_in[4 + L * 12 + 4];
    const float* bv  = (const float*)d_in[4 + L * 12 + 5];
    const float* We  = (const float*)d_in[4 + L * 12 + 6];
    const float* Wsk = (const float*)d_in[4 + L * 12 + 7];
    WP.W[L * 4 + 0] = Wq;  WP.O[L * 4 + 0] = WtAll[L];                      WP.Nc[L * 4 + 0] = 1024;
    WP.W[L * 4 + 1] = Wk;  WP.O[L * 4 + 1] = WtAll[L] + (size_t)1024 * 128; WP.Nc[L * 4 + 1] = 1024;
    WP.W[L * 4 + 2] = Wv;  WP.O[L * 4 + 2] = WtAll[L] + (size_t)2048 * 128; WP.Nc[L * 4 + 2] = 1024;
    WP.W[L * 4 + 3] = Wsk; WP.O[L * 4 + 3] = Wtsk[L];                       WP.Nc[L * 4 + 3] = 128;
    PP.Wq[L] = Wq; PP.We[L] = We; PP.Mt[L] = WtAll[L] + (size_t)3072 * 128;
    PP.bq[L] = bq; PP.bk[L] = bk; PP.bv[L] = bv;
    PP.W2t[L] = W2t[L]; PP.biasAll[L] = biasAll[L];
  }
  k_wt_all<<<dim3(32, 4, 8), 256, 0, stream>>>(WP);
  k_mwt<<<dim3(64, 2), 256, 0, stream>>>(PP);
  k_w2t<<<dim3(256, 2), 256, 0, stream>>>(PP);
  k_bias_all<<<dim3(14, 2), 256, 0, stream>>>(PP);

  const int MT = (NN + 127) / 128;  // 79 row tiles
  for (int L = 0; L < 2; ++L) {
    const float* bsk = (const float*)d_in[4 + L * 12 + 8];
    const float* gnw = (const float*)d_in[4 + L * 12 + 9];
    const float* gnb = (const float*)d_in[4 + L * 12 + 10];
    const float* gnm = (const float*)d_in[4 + L * 12 + 11];
    const ushort* Ain = (L == 0) ? xb : x2b;

    k_gemm_qkvt<<<dim3(28, MT), 256, 0, stream>>>(Ain, WtAll[L], biasAll[L], qt_b, kv8, NN);
    k_fused<<<(NN + 3) / 4, 256, 0, stream>>>(qt_b, kv8, attr_p, src_p, csr_ptr, nodeorder, mbuf, s_b);
    k_gemm_out<<<dim3(1, MT), 256, 0, stream>>>(s_b, Ain, W2t[L], Wtsk[L], bsk, mbuf, hbuf, NN);
    k_gn_partial<<<NB * 4, 256, 0, stream>>>(hbuf, bptrd, part);
    k_gn_apply<<<NN * 128 / 256, 256, 0, stream>>>(
        hbuf, batch, bptrd, part, gnm, gnw, gnb,
        (L == 0) ? (float*)nullptr : (float*)d_out,
        (L == 0) ? x2b : (ushort*)nullptr);
  }
}

// Round 12
// 316.791 us; speedup vs baseline: 1.0680x; 1.0680x over previous
//
#include <hip/hip_runtime.h>
#include <hip/hip_bf16.h>
#include <math.h>

#define NN 10000
#define NE 100000
#define NB 32

typedef __attribute__((ext_vector_type(8))) short short8;
typedef __attribute__((ext_vector_type(4))) float f32x4;
typedef __attribute__((ext_vector_type(2))) float f32x2;
typedef _Float16 h2 __attribute__((ext_vector_type(2)));

union H8 { short8 s; h2 h[4]; };
union HU { _Float16 h; ushort u; };

__device__ inline ushort f2b(float f) {
  union { float f; unsigned u; } a; a.f = f;
  unsigned r = a.u + 0x7fff + ((a.u >> 16) & 1);
  return (ushort)(r >> 16);
}
__device__ inline float bf2f(ushort u) {
  union { unsigned u; float f; } a; a.u = ((unsigned)u) << 16;
  return a.f;
}
__device__ inline ushort f2h(float f) { HU x; x.h = (_Float16)f; return x.u; }
__device__ inline float h2f(ushort u) { HU x; x.u = u; return (float)x.h; }

// ---- fp8 e4m3 encode/decode (HW on gfx950, SW fallback) ----
__device__ inline float e4m3_sw(unsigned b) {
  unsigned s = b & 0x80, e = (b >> 3) & 15, m = b & 7;
  float v = (e == 0) ? (float)m * (1.f / 512.f) : ldexpf((float)(8 + m), (int)e - 10);
  return s ? -v : v;
}
__device__ inline unsigned f2e4m3_sw(float f) {
  unsigned s = (__float_as_uint(f) >> 24) & 0x80;
  float a = fabsf(f);
  if (a < 0.0009765625f) return s;
  if (a >= 448.f) return s | 0x7e;
  if (a < 0.015625f) {
    int q = (int)rintf(a * 512.f);
    return s | (unsigned)q;
  }
  int e2; frexpf(a, &e2);
  int sh = e2 - 4;
  int M = (int)rintf(ldexpf(a, -sh));
  if (M >= 16) { M >>= 1; sh++; }
  int E = sh + 10;
  if (E > 15) return s | 0x7e;
  return s | (unsigned)((E << 3) | (M - 8));
}

#if defined(__has_builtin)
#if __has_builtin(__builtin_amdgcn_cvt_pk_f32_fp8) && __has_builtin(__builtin_amdgcn_cvt_pk_fp8_f32)
#define HW_FP8 1
#endif
#endif

#ifdef HW_FP8
template <bool HI>
__device__ inline f32x2 dec2(unsigned w) {
  return __builtin_amdgcn_cvt_pk_f32_fp8((int)w, HI);
}
template <bool HI>
__device__ inline unsigned enc2(float a, float b, unsigned old) {
  return (unsigned)__builtin_amdgcn_cvt_pk_fp8_f32(a, b, (int)old, HI);
}
#else
template <bool HI>
__device__ inline f32x2 dec2(unsigned w) {
  unsigned x = HI ? (w >> 16) : (w & 0xffff);
  f32x2 r; r[0] = e4m3_sw(x & 0xff); r[1] = e4m3_sw((x >> 8) & 0xff);
  return r;
}
template <bool HI>
__device__ inline unsigned enc2(float a, float b, unsigned old) {
  unsigned pk = f2e4m3_sw(a) | (f2e4m3_sw(b) << 8);
  return HI ? ((old & 0xffffu) | (pk << 16)) : ((old & 0xffff0000u) | pk);
}
#endif

#if defined(__has_builtin)
#if __has_builtin(__builtin_amdgcn_fdot2)
#define FDOT2(a, b, c) __builtin_amdgcn_fdot2((a), (b), (c), false)
#endif
#endif
#ifndef FDOT2
#define FDOT2(a, b, c) ((c) + (float)(a)[0] * (float)(b)[0] + (float)(a)[1] * (float)(b)[1])
#endif

#define GLDS(g, l)                                                        \
  __builtin_amdgcn_global_load_lds(                                       \
      (const __attribute__((address_space(1))) unsigned*)(g),             \
      (__attribute__((address_space(3))) unsigned*)(l), 16, 0, 0)

// ------- qkvt GEMM: A[M,128](bf16) @ Bt[3584,128]^T + bias ->
//         cols [0,1024) f16->qt, [1024,3072) fp8->kv8, [3072,3584) f16->qt(+1024-2048)
__global__ __launch_bounds__(256) void k_gemm_qkvt(
    const ushort* __restrict__ Abf, const ushort* __restrict__ Bt,
    const float* __restrict__ bias, ushort* __restrict__ qt,
    unsigned char* __restrict__ kv8, int M) {
  __shared__ ushort As[128 * 128];
  __shared__ ushort Bs[128 * 128];
  const int tid = threadIdx.x;
  const int l = tid & 63, w = tid >> 6;
  const int wm = w & 1, wn = w >> 1;
  const int row0 = blockIdx.y * 128, col0 = blockIdx.x * 128;
#pragma unroll
  for (int i = 0; i < 8; ++i) {
    int idx = i * 256 + tid;
    int r = idx >> 4, cb = (idx & 15) << 4;
    int scb = cb ^ ((r & 7) << 4);   // pre-swizzled source, linear LDS dest
    GLDS((const char*)Abf + (size_t)(row0 + r) * 256 + scb, (char*)As + idx * 16);
    GLDS((const char*)Bt + (size_t)(col0 + r) * 256 + scb, (char*)Bs + idx * 16);
  }
  __syncthreads();
  f32x4 acc[4][4] = {};
#pragma unroll
  for (int kk = 0; kk < 4; ++kk) {
    short8 af[4], bf[4];
#pragma unroll
    for (int fm = 0; fm < 4; ++fm) {
      int r = wm * 64 + fm * 16 + (l & 15);
      int cb = (kk * 64 + ((l >> 4) << 4)) ^ ((r & 7) << 4);
      af[fm] = *(const short8*)((const char*)As + r * 256 + cb);
    }
#pragma unroll
    for (int fn = 0; fn < 4; ++fn) {
      int r = wn * 64 + fn * 16 + (l & 15);
      int cb = (kk * 64 + ((l >> 4) << 4)) ^ ((r & 7) << 4);
      bf[fn] = *(const short8*)((const char*)Bs + r * 256 + cb);
    }
#pragma unroll
    for (int fm = 0; fm < 4; ++fm)
#pragma unroll
      for (int fn = 0; fn < 4; ++fn)
        acc[fm][fn] = __builtin_amdgcn_mfma_f32_16x16x32_bf16(af[fm], bf[fn], acc[fm][fn], 0, 0, 0);
  }
  // stage acc (f16) into As, swizzled
  __syncthreads();
#pragma unroll
  for (int fm = 0; fm < 4; ++fm) {
    int rloc = wm * 64 + fm * 16 + ((l >> 4) << 2);
#pragma unroll
    for (int fn = 0; fn < 4; ++fn) {
      int cbyte = (wn * 64 + fn * 16 + (l & 15)) * 2;
#pragma unroll
      for (int b = 0; b < 4; ++b) {
        int r = rloc + b;
        *(ushort*)((char*)As + r * 256 + (cbyte ^ ((r & 7) << 4))) = f2h(acc[fm][fn][b]);
      }
    }
  }
  __syncthreads();
  const bool isf16 = (col0 < 1024) || (col0 >= 3072);
#pragma unroll
  for (int it = 0; it < 8; ++it) {
    int idx = it * 256 + tid;
    int r = idx >> 4, cb16 = (idx & 15) << 4;
    int gr = row0 + r;
    if (gr >= M) continue;
    short8 v = *(const short8*)((const char*)As + r * 256 + (cb16 ^ ((r & 7) << 4)));
    int co = cb16 >> 1;  // col offset within 128, multiple of 8
    if (isf16) {
      int qc0 = ((col0 < 1024) ? col0 : (col0 - 2048)) + co;
      short8 o;
#pragma unroll
      for (int j = 0; j < 8; ++j) o[j] = (short)f2h(h2f((ushort)v[j]) + bias[col0 + co + j]);
      *(short8*)(qt + (size_t)gr * 1536 + qc0) = o;
    } else {
      float f[8];
#pragma unroll
      for (int j = 0; j < 8; ++j) f[j] = h2f((ushort)v[j]) + bias[col0 + co + j];
      unsigned w0 = 0, w1 = 0;
      w0 = enc2<false>(f[0], f[1], w0);
      w0 = enc2<true>(f[2], f[3], w0);
      w1 = enc2<false>(f[4], f[5], w1);
      w1 = enc2<true>(f[6], f[7], w1);
      uint2 st; st.x = w0; st.y = w1;
      *(uint2*)(kv8 + (size_t)gr * 2048 + (col0 - 1024) + co) = st;
    }
  }
}

// ------- fused output GEMM: hbuf[M,128] = s_b[M,512]@W2t^T + x[M,128]@Wsk^T + bsk + mbuf ---
__global__ __launch_bounds__(256) void k_gemm_out(
    const ushort* __restrict__ s_b, const ushort* __restrict__ xin,
    const ushort* __restrict__ W2t, const ushort* __restrict__ Wsk,
    const float* __restrict__ bsk, const float* __restrict__ mbuf,
    float* __restrict__ Cf, int M) {
  __shared__ ushort As[128 * 128];
  __shared__ ushort Bs[128 * 128];
  const int tid = threadIdx.x;
  const int l = tid & 63, w = tid >> 6;
  const int wm = w & 1, wn = w >> 1;
  const int row0 = blockIdx.y * 128;
  f32x4 acc[4][4] = {};
  for (int kt = 0; kt < 5; ++kt) {
    if (kt) __syncthreads();
    const char* Ab; const char* Bb; size_t arb, brb; int ko;
    if (kt < 4) { Ab = (const char*)s_b; arb = 1024; Bb = (const char*)W2t; brb = 1024; ko = kt * 256; }
    else        { Ab = (const char*)xin; arb = 256;  Bb = (const char*)Wsk; brb = 256;  ko = 0; }
#pragma unroll
    for (int i = 0; i < 8; ++i) {
      int idx = i * 256 + tid;
      int r = idx >> 4, cb = (idx & 15) << 4;
      int scb = cb ^ ((r & 7) << 4);
      GLDS(Ab + (size_t)(row0 + r) * arb + ko + scb, (char*)As + idx * 16);
      GLDS(Bb + (size_t)r * brb + ko + scb, (char*)Bs + idx * 16);
    }
    __syncthreads();
#pragma unroll
    for (int kk = 0; kk < 4; ++kk) {
      short8 af[4], bf[4];
#pragma unroll
      for (int fm = 0; fm < 4; ++fm) {
        int r = wm * 64 + fm * 16 + (l & 15);
        int cb = (kk * 64 + ((l >> 4) << 4)) ^ ((r & 7) << 4);
        af[fm] = *(const short8*)((const char*)As + r * 256 + cb);
      }
#pragma unroll
      for (int fn = 0; fn < 4; ++fn) {
        int r = wn * 64 + fn * 16 + (l & 15);
        int cb = (kk * 64 + ((l >> 4) << 4)) ^ ((r & 7) << 4);
        bf[fn] = *(const short8*)((const char*)Bs + r * 256 + cb);
      }
#pragma unroll
      for (int fm = 0; fm < 4; ++fm)
#pragma unroll
        for (int fn = 0; fn < 4; ++fn)
          acc[fm][fn] = __builtin_amdgcn_mfma_f32_16x16x32_bf16(af[fm], bf[fn], acc[fm][fn], 0, 0, 0);
    }
  }
#pragma unroll
  for (int fm = 0; fm < 4; ++fm) {
    int row = row0 + wm * 64 + fm * 16 + ((l >> 4) << 2);
#pragma unroll
    for (int fn = 0; fn < 4; ++fn) {
      int col = wn * 64 + fn * 16 + (l & 15);
      if (col >= 128) continue;
      float bb = bsk[col];
#pragma unroll
      for (int b = 0; b < 4; ++b) {
        int rr = row + b;
        if (rr >= M) continue;
        Cf[(size_t)rr * 128 + col] = acc[fm][fn][b] + bb + mbuf[(size_t)rr * 128 + col];
      }
    }
  }
}

// ---------------- weight prep ----------------
struct WtPrep { const float* W[8]; ushort* O[8]; int Nc[8]; };
__global__ void k_wt_all(WtPrep P) {
  const int z = blockIdx.z;
  const int Nc = P.Nc[z];
  if ((int)blockIdx.x * 32 >= Nc) return;
  const float* __restrict__ W = P.W[z];
  ushort* __restrict__ Wt = P.O[z];
  __shared__ float tile[32][33];
  const int t = threadIdx.x, lx = t & 31, ly = t >> 5;
  const int bx = blockIdx.x, by = blockIdx.y;
#pragma unroll
  for (int i = 0; i < 4; ++i)
    tile[ly + i * 8][lx] = W[(by * 32 + ly + i * 8) * Nc + bx * 32 + lx];
  __syncthreads();
#pragma unroll
  for (int i = 0; i < 4; ++i)
    Wt[(size_t)(bx * 32 + ly + i * 8) * 128 + by * 32 + lx] = f2b(tile[lx][ly + i * 8]);
}

struct PrepPtrs {
  const float* Wq[2]; const float* We[2]; ushort* Mt[2];
  const float* bq[2]; const float* bk[2]; const float* bv[2];
  ushort* W2t[2]; float* biasAll[2];
};

// Mt[(h*64+d)*128 + p] = bf16( sum_c Wq[p,h*128+c] * We[d,h*128+c] );  grid (64, 2)
__global__ __launch_bounds__(256) void k_mwt(PrepPtrs P) {
  const int L = blockIdx.y;
  const float* __restrict__ Wq = P.Wq[L];
  const float* __restrict__ We = P.We[L];
  ushort* __restrict__ Mt = P.Mt[L];
  const int h = blockIdx.x >> 3, pt = blockIdx.x & 7;
  const int t = threadIdx.x;
  __shared__ float Wes[64][129];
  __shared__ float Wqs[16][129];
#pragma unroll
  for (int i = 0; i < 32; ++i) {
    int idx = i * 256 + t;
    Wes[idx >> 7][idx & 127] = We[(idx >> 7) * 1024 + h * 128 + (idx & 127)];
  }
#pragma unroll
  for (int i = 0; i < 8; ++i) {
    int idx = i * 256 + t;
    Wqs[idx >> 7][idx & 127] = Wq[(pt * 16 + (idx >> 7)) * 1024 + h * 128 + (idx & 127)];
  }
  __syncthreads();
#pragma unroll
  for (int i = 0; i < 4; ++i) {
    int o = i * 256 + t;
    int d = o & 63, p = o >> 6;
    float s = 0.f;
#pragma unroll 8
    for (int c = 0; c < 128; ++c) s += Wqs[p][c] * Wes[d][c];
    Mt[(size_t)(h * 64 + d) * 128 + pt * 16 + p] = f2b(s);
  }
}

// W2t[c*512 + h*64+d] = bf16( We[d,h*128+c] / 8 );  grid (256, 2)
__global__ void k_w2t(PrepPtrs P) {
  const int L = blockIdx.y;
  int o = blockIdx.x * 256 + threadIdx.x;
  if (o < 128 * 512) {
    int c = o >> 9, hd = o & 511;
    int hh = hd >> 6, d = hd & 63;
    P.W2t[L][o] = f2b(P.We[L][d * 1024 + hh * 128 + c] * 0.125f);
  }
}

// biasAll[0..3071] = cat(bq,bk,bv); biasAll[3072+h*64+d] = bq·We;  grid (14, 2)
__global__ void k_bias_all(PrepPtrs P) {
  const int L = blockIdx.y;
  int o = blockIdx.x * 256 + threadIdx.x;
  if (o < 1024) P.biasAll[L][o] = P.bq[L][o];
  else if (o < 2048) P.biasAll[L][o] = P.bk[L][o - 1024];
  else if (o < 3072) P.biasAll[L][o] = P.bv[L][o - 2048];
  else if (o < 3584) {
    int hd = o - 3072;
    int h = hd >> 6, d = hd & 63;
    float s = 0.f;
    for (int c = 0; c < 128; ++c) s += P.bq[L][h * 128 + c] * P.We[L][d * 1024 + h * 128 + c];
    P.biasAll[L][o] = s;
  }
}

__global__ void k_cvt(const float* __restrict__ in, ushort* __restrict__ out, int n4) {
  int i = blockIdx.x * 256 + threadIdx.x;
  if (i < n4) {
    float4 v = *(const float4*)(in + i * 4);
    ushort4 o;
    o.x = f2b(v.x); o.y = f2b(v.y); o.z = f2b(v.z); o.w = f2b(v.w);
    *(ushort4*)(out + i * 4) = o;
  }
}

// ---------------- CSR build over dst ----------------
__global__ void k_histo(const int* __restrict__ dst, int* __restrict__ cnt) {
  int e = blockIdx.x * 256 + threadIdx.x;
  if (e < NE) atomicAdd(&cnt[dst[e]], 1);
}

__global__ __launch_bounds__(256) void k_scan(const int* __restrict__ cnt,
                                              int* __restrict__ ptr) {
  __shared__ int tsum[256];
  const int t = threadIdx.x;
  const int base = t * 40;
  int s = 0;
  for (int i = 0; i < 40; ++i) { int idx = base + i; if (idx < NN) s += cnt[idx]; }
  tsum[t] = s;
  __syncthreads();
  for (int off = 1; off < 256; off <<= 1) {
    int v = (t >= off) ? tsum[t - off] : 0;
    __syncthreads();
    tsum[t] += v;
    __syncthreads();
  }
  int run = (t == 0) ? 0 : tsum[t - 1];
  for (int i = 0; i < 40; ++i) {
    int idx = base + i;
    if (idx < NN) { ptr[idx] = run; run += cnt[idx]; }
  }
  if (t == 255) ptr[NN] = tsum[255];
}

// countdown scatter: cnt[d] holds degree after histo; no second memset needed
__global__ void k_scatter(const int* __restrict__ dst, const int* __restrict__ ptr,
                          int* __restrict__ cnt, int* __restrict__ eid) {
  int e = blockIdx.x * 256 + threadIdx.x;
  if (e < NE) {
    int d = dst[e];
    int pos = ptr[d] + atomicSub(&cnt[d], 1) - 1;
    eid[pos] = e;
  }
}

// LPT order: counting sort of nodes by degree, DESCENDING. Single block.
__global__ __launch_bounds__(256) void k_sortdeg(const int* __restrict__ ptr,
                                                 int* __restrict__ order) {
  __shared__ int hist[256];
  __shared__ int offs[256];
  __shared__ int fill[256];
  __shared__ int sc[256];
  const int t = threadIdx.x;
  hist[t] = 0;
  __syncthreads();
  for (int n = t; n < NN; n += 256) {
    int d = min(ptr[n + 1] - ptr[n], 255);
    atomicAdd(&hist[d], 1);
  }
  __syncthreads();
  const int rd = 255 - t;
  int v = hist[rd];
  sc[t] = v;
  __syncthreads();
  for (int off = 1; off < 256; off <<= 1) {
    int u = (t >= off) ? sc[t - off] : 0;
    __syncthreads();
    sc[t] += u;
    __syncthreads();
  }
  offs[rd] = sc[t] - v;   // sum of counts of all higher degrees
  fill[rd] = 0;
  __syncthreads();
  for (int n = t; n < NN; n += 256) {
    int d = min(ptr[n + 1] - ptr[n], 255);
    int pos = offs[d] + atomicAdd(&fill[d], 1);
    order[pos] = n;
  }
}

// permute attr (f32->f16) and src into CSR slot order
__global__ void k_permattr(const int* __restrict__ eid, const int* __restrict__ src,
                           const float* __restrict__ attr, int* __restrict__ src_p,
                           ushort* __restrict__ attr_p) {
  int i = blockIdx.x * 256 + threadIdx.x;
  if (i >= NE * 16) return;
  int idx = i >> 4, part = i & 15;
  int e = eid[idx];
  if (part == 0) src_p[idx] = src[e];
  float4 v = *(const float4*)(attr + (size_t)e * 64 + part * 4);
  ushort4 o;
  o.x = f2h(v.x); o.y = f2h(v.y); o.z = f2h(v.z); o.w = f2h(v.w);
  *(ushort4*)(attr_p + (size_t)idx * 64 + part * 4) = o;
}

// ---------------- batch boundaries (batch is sorted) ----------------
__global__ void k_bptr(const int* __restrict__ batch, int* __restrict__ bptr) {
  int b = threadIdx.x;
  if (b > NB) return;
  int lo = 0, hi = NN;
  while (lo < hi) { int mid = (lo + hi) >> 1; if (batch[mid] < b) lo = mid + 1; else hi = mid; }
  bptr[b] = lo;
}

// ---------------- fused attention: 4 independent waves per block (LPT), fp8 k/v ----
// qt row: [q(1024) | t(512)] f16. kv8 row: [k(1024) | v(1024)] fp8 e4m3.
// lane l owns channels l*16..l*16+15 (head h=l>>3, sub i=l&7). No __syncthreads.
// NOTE: no min-waves clamp (R9: 8 waves/EU forced VGPR 52->32, spilled).
// NOTE: 1-deep prefetch only (R11: 2-deep pushed VGPR past 64 -> 4 waves/SIMD, regressed).
__global__ __launch_bounds__(256) void k_fused(
    const ushort* __restrict__ qt, const unsigned char* __restrict__ kv8,
    const ushort* __restrict__ attr_p, const int* __restrict__ src_p,
    const int* __restrict__ ptr, const int* __restrict__ order,
    float* __restrict__ mbuf, ushort* __restrict__ s_b) {
  const int slot = blockIdx.x * 4 + (threadIdx.x >> 6);
  if (slot >= NN) return;
  const int n = order[slot];
  const int l = threadIdx.x & 63;
  const int i = l & 7;
  float qf[16];
  {
    H8 q0, q1;
    const ushort* qr = qt + (size_t)n * 1536 + l * 16;
    q0.s = *(const short8*)qr;
    q1.s = *(const short8*)(qr + 8);
#pragma unroll
    for (int j = 0; j < 8; ++j) { qf[j] = h2f((ushort)q0.s[j]); qf[8 + j] = h2f((ushort)q1.s[j]); }
  }
  H8 tv;
  tv.s = *(const short8*)(qt + (size_t)n * 1536 + 1024 + l * 8);
  const int beg = ptr[n], end = ptr[n + 1];
  float m = -1e30f, den = 0.f;
  float acc[16] = {};
  float sa[8] = {};
  uint4 kw, vw; H8 av;
  if (beg < end) {
    int s0 = src_p[beg];
    const unsigned char* kr = kv8 + (size_t)s0 * 2048 + l * 16;
    kw = *(const uint4*)kr;
    vw = *(const uint4*)(kr + 1024);
    av.s = *(const short8*)(attr_p + (size_t)beg * 64 + i * 8);
  }
  for (int idx = beg; idx < end; ++idx) {
    uint4 ckw = kw, cvw = vw; H8 cav = av;
    int nidx = (idx + 1 < end) ? idx + 1 : idx;
    int ns = src_p[nidx];
    const unsigned char* kr = kv8 + (size_t)ns * 2048 + l * 16;
    kw = *(const uint4*)kr;
    vw = *(const uint4*)(kr + 1024);
    av.s = *(const short8*)(attr_p + (size_t)nidx * 64 + i * 8);
    float p = 0.f;
    {
      const unsigned* kws = (const unsigned*)&ckw;
#pragma unroll
      for (int j = 0; j < 4; ++j) {
        f32x2 lo = dec2<false>(kws[j]), hi = dec2<true>(kws[j]);
        p += qf[4 * j] * lo[0] + qf[4 * j + 1] * lo[1]
           + qf[4 * j + 2] * hi[0] + qf[4 * j + 3] * hi[1];
      }
    }
#pragma unroll
    for (int j = 0; j < 4; ++j) p = FDOT2(tv.h[j], cav.h[j], p);
    p += __shfl_xor(p, 1, 64);
    p += __shfl_xor(p, 2, 64);
    p += __shfl_xor(p, 4, 64);
    p *= 0.12751593061420927f;  // (1/sqrt(128)) * log2(e) -> exp2 domain
    float mn = fmaxf(m, p);
    float r = exp2f(m - mn);
    float ex = exp2f(p - mn);
    den = den * r + ex;
    {
      const unsigned* vws = (const unsigned*)&cvw;
#pragma unroll
      for (int j = 0; j < 4; ++j) {
        f32x2 lo = dec2<false>(vws[j]), hi = dec2<true>(vws[j]);
        acc[4 * j]     = acc[4 * j]     * r + ex * lo[0];
        acc[4 * j + 1] = acc[4 * j + 1] * r + ex * lo[1];
        acc[4 * j + 2] = acc[4 * j + 2] * r + ex * hi[0];
        acc[4 * j + 3] = acc[4 * j + 3] * r + ex * hi[1];
      }
    }
#pragma unroll
    for (int j = 0; j < 4; ++j) {
      sa[2 * j]     = sa[2 * j]     * r + ex * (float)cav.h[j][0];
      sa[2 * j + 1] = sa[2 * j + 1] * r + ex * (float)cav.h[j][1];
    }
    m = mn;
  }
  const float invd = den > 0.f ? 1.f / den : 0.f;
  short8 sb;
#pragma unroll
  for (int j = 0; j < 8; ++j) sb[j] = (short)f2b(sa[j] * invd);
  *(short8*)(s_b + (size_t)n * 512 + l * 8) = sb;
#pragma unroll
  for (int j = 0; j < 16; ++j) {
    float a = acc[j] * invd;
    a += __shfl_xor(a, 8, 64);
    a += __shfl_xor(a, 16, 64);
    a += __shfl_xor(a, 32, 64);
    acc[j] = a;
  }
  if (l < 8) {  // h==0 lanes, i==l
    float* mb = mbuf + (size_t)n * 128 + l * 16;
#pragma unroll
    for (int j = 0; j < 16; j += 4) {
      float4 o = make_float4(acc[j] * 0.125f, acc[j + 1] * 0.125f,
                             acc[j + 2] * 0.125f, acc[j + 3] * 0.125f);
      *(float4*)(mb + j) = o;
    }
  }
}

// ---------------- GraphNorm: atomic-free partials, finalize in apply ----
// part layout: gs[chunk][b][c] then gs2[chunk][b][c], chunk in 0..3
__global__ __launch_bounds__(256) void k_gn_partial(
    const float* __restrict__ x, const int* __restrict__ bptr,
    float* __restrict__ part) {
  const int b = blockIdx.x >> 2, chunk = blockIdx.x & 3;
  const int t = threadIdx.x;
  const int c = t & 127, half = t >> 7;
  const int beg = bptr[b], end = bptr[b + 1];
  float s = 0.f, s2 = 0.f;
  for (int n = beg + chunk * 2 + half; n < end; n += 8) {
    float v = x[(size_t)n * 128 + c];
    s += v; s2 += v * v;
  }
  __shared__ float r1[256];
  __shared__ float r2[256];
  r1[t] = s; r2[t] = s2;
  __syncthreads();
  if (half == 0) {
    part[((size_t)chunk * NB + b) * 128 + c] = r1[c] + r1[c + 128];
    part[4 * NB * 128 + ((size_t)chunk * NB + b) * 128 + c] = r2[c] + r2[c + 128];
  }
}

__global__ void k_gn_apply(const float* __restrict__ x, const int* __restrict__ batch,
                           const int* __restrict__ bptr, const float* __restrict__ part,
                           const float* __restrict__ ms, const float* __restrict__ wgt,
                           const float* __restrict__ gnb,
                           float* __restrict__ fout, ushort* __restrict__ bout) {
  int i = blockIdx.x * 256 + threadIdx.x;
  int n = i >> 7, c = i & 127;
  int b = batch[n];
  float S = 0.f, S2 = 0.f;
#pragma unroll
  for (int ch = 0; ch < 4; ++ch) {
    S  += part[((size_t)ch * NB + b) * 128 + c];
    S2 += part[4 * NB * 128 + ((size_t)ch * NB + b) * 128 + c];
  }
  float cnt = fmaxf((float)(bptr[b + 1] - bptr[b]), 1.f);
  float mean = S / cnt;
  float mm = mean * ms[c];
  float var = S2 / cnt - 2.f * mm * mean + mm * mm;
  float o = (x[i] - mm) * rsqrtf(var + 1e-5f) * wgt[c] + gnb[c];
  o = o > 0.f ? o : 0.01f * o;
  if (fout) fout[i] = o;
  if (bout) bout[i] = f2b(o);
}

extern "C" void kernel_launch(void* const* d_in, const int* in_sizes, int n_in,
                              void* d_out, int out_size, void* d_ws, size_t ws_size,
                              hipStream_t stream) {
  const float* x     = (const float*)d_in[0];
  const int*   index = (const int*)d_in[1];
  const float* attr  = (const float*)d_in[2];
  const int*   batch = (const int*)d_in[3];
  const int* srcArr = index;
  const int* dstArr = index + NE;

  char* p = (char*)d_ws;
  auto take = [&](size_t bytes) {
    char* r = p;
    p += (bytes + 255) & ~(size_t)255;
    return (void*)r;
  };
  ushort* qt_b   = (ushort*)take((size_t)NN * 1536 * 2);   // f16 [q|t]
  unsigned char* kv8 = (unsigned char*)take((size_t)NN * 2048);  // fp8 [k|v]
  ushort* s_b    = (ushort*)take((size_t)NN * 512 * 2);    // bf16
  float*  mbuf   = (float*)take((size_t)NN * 128 * 4);
  float*  hbuf   = (float*)take((size_t)NN * 128 * 4);
  ushort* xb     = (ushort*)take((size_t)NN * 128 * 2);    // bf16
  ushort* x2b    = (ushort*)take((size_t)NN * 128 * 2);    // bf16
  ushort* attr_p = (ushort*)take((size_t)NE * 64 * 2);     // f16, CSR order
  int*    src_p  = (int*)take((size_t)NE * 4);
  float*  part   = (float*)take((size_t)4 * NB * 128 * 2 * 4);
  int* csr_ptr   = (int*)take((size_t)(NN + 1) * 4);
  int* csr_cnt   = (int*)take((size_t)NN * 4);
  int* csr_eid   = (int*)take((size_t)NE * 4);
  int* nodeorder = (int*)take((size_t)NN * 4);
  int* bptrd     = (int*)take((size_t)(NB + 1) * 4);
  ushort* WtAll[2]; ushort* Wtsk[2]; ushort* W2t[2];
  float* biasAll[2];
  for (int L = 0; L < 2; ++L) {
    WtAll[L]   = (ushort*)take((size_t)3584 * 128 * 2);  // [q|k|v|t] rows, bf16
    Wtsk[L]    = (ushort*)take((size_t)128 * 128 * 2);
    W2t[L]     = (ushort*)take((size_t)128 * 512 * 2);
    biasAll[L] = (float*)take((size_t)3584 * 4);
  }

  // ---- CSR over dst + LPT order + batch boundaries + conversions ----
  hipMemsetAsync(csr_cnt, 0, NN * 4, stream);
  k_histo<<<(NE + 255) / 256, 256, 0, stream>>>(dstArr, csr_cnt);
  k_scan<<<1, 256, 0, stream>>>(csr_cnt, csr_ptr);
  k_scatter<<<(NE + 255) / 256, 256, 0, stream>>>(dstArr, csr_ptr, csr_cnt, csr_eid);
  k_sortdeg<<<1, 256, 0, stream>>>(csr_ptr, nodeorder);
  k_permattr<<<(NE * 16 + 255) / 256, 256, 0, stream>>>(csr_eid, srcArr, attr, src_p, attr_p);
  k_bptr<<<1, 64, 0, stream>>>(batch, bptrd);
  k_cvt<<<(NN * 128 / 4 + 255) / 256, 256, 0, stream>>>(x, xb, NN * 128 / 4);

  // ---- weight prep (all matrices, both layers) ----
  WtPrep WP;
  PrepPtrs PP;
  for (int L = 0; L < 2; ++L) {
    const float* Wq  = (const float*)d_in[4 + L * 12 + 0];
    const float* bq  = (const float*)d_in[4 + L * 12 + 1];
    const float* Wk  = (const float*)d_in[4 + L * 12 + 2];
    const float* bk  = (const float*)d_in[4 + L * 12 + 3];
    const float* Wv  = (const float*)d_in[4 + L * 12 + 4];
    const float* bv  = (const float*)d_in[4 + L * 12 + 5];
    const float* We  = (const float*)d_in[4 + L * 12 + 6];
    const float* Wsk = (const float*)d_in[4 + L * 12 + 7];
    WP.W[L * 4 + 0] = Wq;  WP.O[L * 4 + 0] = WtAll[L];                      WP.Nc[L * 4 + 0] = 1024;
    WP.W[L * 4 + 1] = Wk;  WP.O[L * 4 + 1] = WtAll[L] + (size_t)1024 * 128; WP.Nc[L * 4 + 1] = 1024;
    WP.W[L * 4 + 2] = Wv;  WP.O[L * 4 + 2] = WtAll[L] + (size_t)2048 * 128; WP.Nc[L * 4 + 2] = 1024;
    WP.W[L * 4 + 3] = Wsk; WP.O[L * 4 + 3] = Wtsk[L];                       WP.Nc[L * 4 + 3] = 128;
    PP.Wq[L] = Wq; PP.We[L] = We; PP.Mt[L] = WtAll[L] + (size_t)3072 * 128;
    PP.bq[L] = bq; PP.bk[L] = bk; PP.bv[L] = bv;
    PP.W2t[L] = W2t[L]; PP.biasAll[L] = biasAll[L];
  }
  k_wt_all<<<dim3(32, 4, 8), 256, 0, stream>>>(WP);
  k_mwt<<<dim3(64, 2), 256, 0, stream>>>(PP);
  k_w2t<<<dim3(256, 2), 256, 0, stream>>>(PP);
  k_bias_all<<<dim3(14, 2), 256, 0, stream>>>(PP);

  const int MT = (NN + 127) / 128;  // 79 row tiles
  for (int L = 0; L < 2; ++L) {
    const float* bsk = (const float*)d_in[4 + L * 12 + 8];
    const float* gnw = (const float*)d_in[4 + L * 12 + 9];
    const float* gnb = (const float*)d_in[4 + L * 12 + 10];
    const float* gnm = (const float*)d_in[4 + L * 12 + 11];
    const ushort* Ain = (L == 0) ? xb : x2b;

    k_gemm_qkvt<<<dim3(28, MT), 256, 0, stream>>>(Ain, WtAll[L], biasAll[L], qt_b, kv8, NN);
    k_fused<<<(NN + 3) / 4, 256, 0, stream>>>(qt_b, kv8, attr_p, src_p, csr_ptr, nodeorder, mbuf, s_b);
    k_gemm_out<<<dim3(1, MT), 256, 0, stream>>>(s_b, Ain, W2t[L], Wtsk[L], bsk, mbuf, hbuf, NN);
    k_gn_partial<<<NB * 4, 256, 0, stream>>>(hbuf, bptrd, part);
    k_gn_apply<<<NN * 128 / 256, 256, 0, stream>>>(
        hbuf, batch, bptrd, part, gnm, gnw, gnb,
        (L == 0) ? (float*)nullptr : (float*)d_out,
        (L == 0) ? x2b : (ushort*)nullptr);
  }
}

// Round 13
// 293.848 us; speedup vs baseline: 1.1513x; 1.0781x over previous
//
#include <hip/hip_runtime.h>
#include <hip/hip_bf16.h>
#include <math.h>

#define NN 10000
#define NE 100000
#define NB 32

typedef __attribute__((ext_vector_type(8))) short short8;
typedef __attribute__((ext_vector_type(4))) float f32x4;
typedef __attribute__((ext_vector_type(2))) float f32x2;
typedef _Float16 h2 __attribute__((ext_vector_type(2)));

union H8 { short8 s; h2 h[4]; };
union HU { _Float16 h; ushort u; };

__device__ inline ushort f2b(float f) {
  union { float f; unsigned u; } a; a.f = f;
  unsigned r = a.u + 0x7fff + ((a.u >> 16) & 1);
  return (ushort)(r >> 16);
}
__device__ inline float bf2f(ushort u) {
  union { unsigned u; float f; } a; a.u = ((unsigned)u) << 16;
  return a.f;
}
__device__ inline ushort f2h(float f) { HU x; x.h = (_Float16)f; return x.u; }
__device__ inline float h2f(ushort u) { HU x; x.u = u; return (float)x.h; }

// ---- fp8 e4m3 encode/decode (HW on gfx950, SW fallback) ----
__device__ inline float e4m3_sw(unsigned b) {
  unsigned s = b & 0x80, e = (b >> 3) & 15, m = b & 7;
  float v = (e == 0) ? (float)m * (1.f / 512.f) : ldexpf((float)(8 + m), (int)e - 10);
  return s ? -v : v;
}
__device__ inline unsigned f2e4m3_sw(float f) {
  unsigned s = (__float_as_uint(f) >> 24) & 0x80;
  float a = fabsf(f);
  if (a < 0.0009765625f) return s;
  if (a >= 448.f) return s | 0x7e;
  if (a < 0.015625f) {
    int q = (int)rintf(a * 512.f);
    return s | (unsigned)q;
  }
  int e2; frexpf(a, &e2);
  int sh = e2 - 4;
  int M = (int)rintf(ldexpf(a, -sh));
  if (M >= 16) { M >>= 1; sh++; }
  int E = sh + 10;
  if (E > 15) return s | 0x7e;
  return s | (unsigned)((E << 3) | (M - 8));
}

#if defined(__has_builtin)
#if __has_builtin(__builtin_amdgcn_cvt_pk_f32_fp8) && __has_builtin(__builtin_amdgcn_cvt_pk_fp8_f32)
#define HW_FP8 1
#endif
#endif

#ifdef HW_FP8
template <bool HI>
__device__ inline f32x2 dec2(unsigned w) {
  return __builtin_amdgcn_cvt_pk_f32_fp8((int)w, HI);
}
template <bool HI>
__device__ inline unsigned enc2(float a, float b, unsigned old) {
  return (unsigned)__builtin_amdgcn_cvt_pk_fp8_f32(a, b, (int)old, HI);
}
#else
template <bool HI>
__device__ inline f32x2 dec2(unsigned w) {
  unsigned x = HI ? (w >> 16) : (w & 0xffff);
  f32x2 r; r[0] = e4m3_sw(x & 0xff); r[1] = e4m3_sw((x >> 8) & 0xff);
  return r;
}
template <bool HI>
__device__ inline unsigned enc2(float a, float b, unsigned old) {
  unsigned pk = f2e4m3_sw(a) | (f2e4m3_sw(b) << 8);
  return HI ? ((old & 0xffffu) | (pk << 16)) : ((old & 0xffff0000u) | pk);
}
#endif

#if defined(__has_builtin)
#if __has_builtin(__builtin_amdgcn_fdot2)
#define FDOT2(a, b, c) __builtin_amdgcn_fdot2((a), (b), (c), false)
#endif
#endif
#ifndef FDOT2
#define FDOT2(a, b, c) ((c) + (float)(a)[0] * (float)(b)[0] + (float)(a)[1] * (float)(b)[1])
#endif

#define GLDS(g, l)                                                        \
  __builtin_amdgcn_global_load_lds(                                       \
      (const __attribute__((address_space(1))) unsigned*)(g),             \
      (__attribute__((address_space(3))) unsigned*)(l), 16, 0, 0)

// ------- qkvt GEMM: A[M,128](bf16) @ Bt[3584,128]^T + bias ->
//         cols [0,1024) f16->qt, [1024,3072) fp8->kv8, [3072,3584) f16->qt(+1024-2048)
__global__ __launch_bounds__(256) void k_gemm_qkvt(
    const ushort* __restrict__ Abf, const ushort* __restrict__ Bt,
    const float* __restrict__ bias, ushort* __restrict__ qt,
    unsigned char* __restrict__ kv8, int M) {
  __shared__ ushort As[128 * 128];
  __shared__ ushort Bs[128 * 128];
  const int tid = threadIdx.x;
  const int l = tid & 63, w = tid >> 6;
  const int wm = w & 1, wn = w >> 1;
  const int row0 = blockIdx.y * 128, col0 = blockIdx.x * 128;
#pragma unroll
  for (int i = 0; i < 8; ++i) {
    int idx = i * 256 + tid;
    int r = idx >> 4, cb = (idx & 15) << 4;
    int scb = cb ^ ((r & 7) << 4);   // pre-swizzled source, linear LDS dest
    GLDS((const char*)Abf + (size_t)(row0 + r) * 256 + scb, (char*)As + idx * 16);
    GLDS((const char*)Bt + (size_t)(col0 + r) * 256 + scb, (char*)Bs + idx * 16);
  }
  __syncthreads();
  f32x4 acc[4][4] = {};
#pragma unroll
  for (int kk = 0; kk < 4; ++kk) {
    short8 af[4], bf[4];
#pragma unroll
    for (int fm = 0; fm < 4; ++fm) {
      int r = wm * 64 + fm * 16 + (l & 15);
      int cb = (kk * 64 + ((l >> 4) << 4)) ^ ((r & 7) << 4);
      af[fm] = *(const short8*)((const char*)As + r * 256 + cb);
    }
#pragma unroll
    for (int fn = 0; fn < 4; ++fn) {
      int r = wn * 64 + fn * 16 + (l & 15);
      int cb = (kk * 64 + ((l >> 4) << 4)) ^ ((r & 7) << 4);
      bf[fn] = *(const short8*)((const char*)Bs + r * 256 + cb);
    }
#pragma unroll
    for (int fm = 0; fm < 4; ++fm)
#pragma unroll
      for (int fn = 0; fn < 4; ++fn)
        acc[fm][fn] = __builtin_amdgcn_mfma_f32_16x16x32_bf16(af[fm], bf[fn], acc[fm][fn], 0, 0, 0);
  }
  // stage acc (f16) into As, swizzled
  __syncthreads();
#pragma unroll
  for (int fm = 0; fm < 4; ++fm) {
    int rloc = wm * 64 + fm * 16 + ((l >> 4) << 2);
#pragma unroll
    for (int fn = 0; fn < 4; ++fn) {
      int cbyte = (wn * 64 + fn * 16 + (l & 15)) * 2;
#pragma unroll
      for (int b = 0; b < 4; ++b) {
        int r = rloc + b;
        *(ushort*)((char*)As + r * 256 + (cbyte ^ ((r & 7) << 4))) = f2h(acc[fm][fn][b]);
      }
    }
  }
  __syncthreads();
  const bool isf16 = (col0 < 1024) || (col0 >= 3072);
#pragma unroll
  for (int it = 0; it < 8; ++it) {
    int idx = it * 256 + tid;
    int r = idx >> 4, cb16 = (idx & 15) << 4;
    int gr = row0 + r;
    if (gr >= M) continue;
    short8 v = *(const short8*)((const char*)As + r * 256 + (cb16 ^ ((r & 7) << 4)));
    int co = cb16 >> 1;  // col offset within 128, multiple of 8
    if (isf16) {
      int qc0 = ((col0 < 1024) ? col0 : (col0 - 2048)) + co;
      short8 o;
#pragma unroll
      for (int j = 0; j < 8; ++j) o[j] = (short)f2h(h2f((ushort)v[j]) + bias[col0 + co + j]);
      *(short8*)(qt + (size_t)gr * 1536 + qc0) = o;
    } else {
      float f[8];
#pragma unroll
      for (int j = 0; j < 8; ++j) f[j] = h2f((ushort)v[j]) + bias[col0 + co + j];
      unsigned w0 = 0, w1 = 0;
      w0 = enc2<false>(f[0], f[1], w0);
      w0 = enc2<true>(f[2], f[3], w0);
      w1 = enc2<false>(f[4], f[5], w1);
      w1 = enc2<true>(f[6], f[7], w1);
      uint2 st; st.x = w0; st.y = w1;
      *(uint2*)(kv8 + (size_t)gr * 2048 + (col0 - 1024) + co) = st;
    }
  }
}

// ------- fused output GEMM: hbuf[M,128] = s_b[M,512]@W2t^T + x[M,128]@Wsk^T + bsk + mbuf ---
__global__ __launch_bounds__(256) void k_gemm_out(
    const ushort* __restrict__ s_b, const ushort* __restrict__ xin,
    const ushort* __restrict__ W2t, const ushort* __restrict__ Wsk,
    const float* __restrict__ bsk, const float* __restrict__ mbuf,
    float* __restrict__ Cf, int M) {
  __shared__ ushort As[128 * 128];
  __shared__ ushort Bs[128 * 128];
  const int tid = threadIdx.x;
  const int l = tid & 63, w = tid >> 6;
  const int wm = w & 1, wn = w >> 1;
  const int row0 = blockIdx.y * 128;
  f32x4 acc[4][4] = {};
  for (int kt = 0; kt < 5; ++kt) {
    if (kt) __syncthreads();
    const char* Ab; const char* Bb; size_t arb, brb; int ko;
    if (kt < 4) { Ab = (const char*)s_b; arb = 1024; Bb = (const char*)W2t; brb = 1024; ko = kt * 256; }
    else        { Ab = (const char*)xin; arb = 256;  Bb = (const char*)Wsk; brb = 256;  ko = 0; }
#pragma unroll
    for (int i = 0; i < 8; ++i) {
      int idx = i * 256 + tid;
      int r = idx >> 4, cb = (idx & 15) << 4;
      int scb = cb ^ ((r & 7) << 4);
      GLDS(Ab + (size_t)(row0 + r) * arb + ko + scb, (char*)As + idx * 16);
      GLDS(Bb + (size_t)r * brb + ko + scb, (char*)Bs + idx * 16);
    }
    __syncthreads();
#pragma unroll
    for (int kk = 0; kk < 4; ++kk) {
      short8 af[4], bf[4];
#pragma unroll
      for (int fm = 0; fm < 4; ++fm) {
        int r = wm * 64 + fm * 16 + (l & 15);
        int cb = (kk * 64 + ((l >> 4) << 4)) ^ ((r & 7) << 4);
        af[fm] = *(const short8*)((const char*)As + r * 256 + cb);
      }
#pragma unroll
      for (int fn = 0; fn < 4; ++fn) {
        int r = wn * 64 + fn * 16 + (l & 15);
        int cb = (kk * 64 + ((l >> 4) << 4)) ^ ((r & 7) << 4);
        bf[fn] = *(const short8*)((const char*)Bs + r * 256 + cb);
      }
#pragma unroll
      for (int fm = 0; fm < 4; ++fm)
#pragma unroll
        for (int fn = 0; fn < 4; ++fn)
          acc[fm][fn] = __builtin_amdgcn_mfma_f32_16x16x32_bf16(af[fm], bf[fn], acc[fm][fn], 0, 0, 0);
    }
  }
#pragma unroll
  for (int fm = 0; fm < 4; ++fm) {
    int row = row0 + wm * 64 + fm * 16 + ((l >> 4) << 2);
#pragma unroll
    for (int fn = 0; fn < 4; ++fn) {
      int col = wn * 64 + fn * 16 + (l & 15);
      if (col >= 128) continue;
      float bb = bsk[col];
#pragma unroll
      for (int b = 0; b < 4; ++b) {
        int rr = row + b;
        if (rr >= M) continue;
        Cf[(size_t)rr * 128 + col] = acc[fm][fn][b] + bb + mbuf[(size_t)rr * 128 + col];
      }
    }
  }
}

// ---------------- weight prep ----------------
struct WtPrep { const float* W[8]; ushort* O[8]; int Nc[8]; };
__global__ void k_wt_all(WtPrep P) {
  const int z = blockIdx.z;
  const int Nc = P.Nc[z];
  if ((int)blockIdx.x * 32 >= Nc) return;
  const float* __restrict__ W = P.W[z];
  ushort* __restrict__ Wt = P.O[z];
  __shared__ float tile[32][33];
  const int t = threadIdx.x, lx = t & 31, ly = t >> 5;
  const int bx = blockIdx.x, by = blockIdx.y;
#pragma unroll
  for (int i = 0; i < 4; ++i)
    tile[ly + i * 8][lx] = W[(by * 32 + ly + i * 8) * Nc + bx * 32 + lx];
  __syncthreads();
#pragma unroll
  for (int i = 0; i < 4; ++i)
    Wt[(size_t)(bx * 32 + ly + i * 8) * 128 + by * 32 + lx] = f2b(tile[lx][ly + i * 8]);
}

struct PrepPtrs {
  const float* Wq[2]; const float* We[2]; ushort* Mt[2];
  const float* bq[2]; const float* bk[2]; const float* bv[2];
  ushort* W2t[2]; float* biasAll[2];
};

// Mt[(h*64+d)*128 + p] = bf16( sum_c Wq[p,h*128+c] * We[d,h*128+c] );  grid (64, 2)
__global__ __launch_bounds__(256) void k_mwt(PrepPtrs P) {
  const int L = blockIdx.y;
  const float* __restrict__ Wq = P.Wq[L];
  const float* __restrict__ We = P.We[L];
  ushort* __restrict__ Mt = P.Mt[L];
  const int h = blockIdx.x >> 3, pt = blockIdx.x & 7;
  const int t = threadIdx.x;
  __shared__ float Wes[64][129];
  __shared__ float Wqs[16][129];
#pragma unroll
  for (int i = 0; i < 32; ++i) {
    int idx = i * 256 + t;
    Wes[idx >> 7][idx & 127] = We[(idx >> 7) * 1024 + h * 128 + (idx & 127)];
  }
#pragma unroll
  for (int i = 0; i < 8; ++i) {
    int idx = i * 256 + t;
    Wqs[idx >> 7][idx & 127] = Wq[(pt * 16 + (idx >> 7)) * 1024 + h * 128 + (idx & 127)];
  }
  __syncthreads();
#pragma unroll
  for (int i = 0; i < 4; ++i) {
    int o = i * 256 + t;
    int d = o & 63, p = o >> 6;
    float s = 0.f;
#pragma unroll 8
    for (int c = 0; c < 128; ++c) s += Wqs[p][c] * Wes[d][c];
    Mt[(size_t)(h * 64 + d) * 128 + pt * 16 + p] = f2b(s);
  }
}

// merged: o<65536 -> W2t[c*512+h*64+d] = bf16(We[d,h*128+c]/8); else biasAll; grid (270, 2)
__global__ void k_w2t_bias(PrepPtrs P) {
  const int L = blockIdx.y;
  int o = blockIdx.x * 256 + threadIdx.x;
  if (o < 128 * 512) {
    int c = o >> 9, hd = o & 511;
    int hh = hd >> 6, d = hd & 63;
    P.W2t[L][o] = f2b(P.We[L][d * 1024 + hh * 128 + c] * 0.125f);
  } else {
    int o2 = o - 128 * 512;
    if (o2 >= 3584) return;
    if (o2 < 1024) P.biasAll[L][o2] = P.bq[L][o2];
    else if (o2 < 2048) P.biasAll[L][o2] = P.bk[L][o2 - 1024];
    else if (o2 < 3072) P.biasAll[L][o2] = P.bv[L][o2 - 2048];
    else {
      int hd = o2 - 3072;
      int h = hd >> 6, d = hd & 63;
      float s = 0.f;
      for (int c = 0; c < 128; ++c) s += P.bq[L][h * 128 + c] * P.We[L][d * 1024 + h * 128 + c];
      P.biasAll[L][o2] = s;
    }
  }
}

// ---------------- CSR build over dst (+ batch boundaries merged) ----------------
// blocks [0, NB_HISTO): histogram; block NB_HISTO: bptr binary search (batch sorted)
__global__ void k_histo_bptr(const int* __restrict__ dst, int* __restrict__ cnt,
                             const int* __restrict__ batch, int* __restrict__ bptr,
                             int nb_histo) {
  if ((int)blockIdx.x < nb_histo) {
    int e = blockIdx.x * 256 + threadIdx.x;
    if (e < NE) atomicAdd(&cnt[dst[e]], 1);
  } else {
    int b = threadIdx.x;
    if (b > NB) return;
    int lo = 0, hi = NN;
    while (lo < hi) { int mid = (lo + hi) >> 1; if (batch[mid] < b) lo = mid + 1; else hi = mid; }
    bptr[b] = lo;
  }
}

// merged scan + LPT counting sort (single block, 256 threads)
__global__ __launch_bounds__(256) void k_scan_sort(const int* __restrict__ cnt,
                                                   int* __restrict__ ptr,
                                                   int* __restrict__ order) {
  __shared__ int tsum[256];
  __shared__ int hist[256];
  __shared__ int offs[256];
  __shared__ int fill[256];
  __shared__ int sc[256];
  const int t = threadIdx.x;
  // --- exclusive scan of cnt -> ptr ---
  const int base = t * 40;
  int s = 0;
  for (int i = 0; i < 40; ++i) { int idx = base + i; if (idx < NN) s += cnt[idx]; }
  tsum[t] = s;
  hist[t] = 0;
  __syncthreads();
  for (int off = 1; off < 256; off <<= 1) {
    int v = (t >= off) ? tsum[t - off] : 0;
    __syncthreads();
    tsum[t] += v;
    __syncthreads();
  }
  int run = (t == 0) ? 0 : tsum[t - 1];
  for (int i = 0; i < 40; ++i) {
    int idx = base + i;
    if (idx < NN) { ptr[idx] = run; run += cnt[idx]; }
  }
  if (t == 255) ptr[NN] = tsum[255];
  // --- LPT counting sort by degree (descending), degrees from cnt ---
  for (int n = t; n < NN; n += 256) {
    int d = min(cnt[n], 255);
    atomicAdd(&hist[d], 1);
  }
  __syncthreads();
  const int rd = 255 - t;
  int v = hist[rd];
  sc[t] = v;
  __syncthreads();
  for (int off = 1; off < 256; off <<= 1) {
    int u = (t >= off) ? sc[t - off] : 0;
    __syncthreads();
    sc[t] += u;
    __syncthreads();
  }
  offs[rd] = sc[t] - v;   // count of all higher degrees
  fill[rd] = 0;
  __syncthreads();
  for (int n = t; n < NN; n += 256) {
    int d = min(cnt[n], 255);
    int pos = offs[d] + atomicAdd(&fill[d], 1);
    order[pos] = n;
  }
}

// countdown scatter: cnt[d] holds degree after histo; no second memset needed
__global__ void k_scatter(const int* __restrict__ dst, const int* __restrict__ ptr,
                          int* __restrict__ cnt, int* __restrict__ eid) {
  int e = blockIdx.x * 256 + threadIdx.x;
  if (e < NE) {
    int d = dst[e];
    int pos = ptr[d] + atomicSub(&cnt[d], 1) - 1;
    eid[pos] = e;
  }
}

// merged: permute attr (f32->f16) + src into CSR order, then x f32->bf16 conversion
__global__ void k_permattr_cvt(const int* __restrict__ eid, const int* __restrict__ src,
                               const float* __restrict__ attr, int* __restrict__ src_p,
                               ushort* __restrict__ attr_p,
                               const float* __restrict__ x, ushort* __restrict__ xb) {
  int i = blockIdx.x * 256 + threadIdx.x;
  if (i < NE * 16) {
    int idx = i >> 4, part = i & 15;
    int e = eid[idx];
    if (part == 0) src_p[idx] = src[e];
    float4 v = *(const float4*)(attr + (size_t)e * 64 + part * 4);
    ushort4 o;
    o.x = f2h(v.x); o.y = f2h(v.y); o.z = f2h(v.z); o.w = f2h(v.w);
    *(ushort4*)(attr_p + (size_t)idx * 64 + part * 4) = o;
  } else {
    int j = i - NE * 16;
    if (j >= NN * 128 / 4) return;
    float4 v = *(const float4*)(x + j * 4);
    ushort4 o;
    o.x = f2b(v.x); o.y = f2b(v.y); o.z = f2b(v.z); o.w = f2b(v.w);
    *(ushort4*)(xb + j * 4) = o;
  }
}

// ---------------- fused attention: 4 independent waves per block (LPT), fp8 k/v ----
// qt row: [q(1024) | t(512)] f16. kv8 row: [k(1024) | v(1024)] fp8 e4m3.
// lane l owns channels l*16..l*16+15 (head h=l>>3, sub i=l&7). No __syncthreads.
// NOTE: no min-waves clamp (R9: 8 waves/EU forced VGPR 52->32, spilled).
// NOTE: 1-deep prefetch only (R11: 2-deep pushed VGPR past 64 -> 4 waves/SIMD, regressed).
__global__ __launch_bounds__(256) void k_fused(
    const ushort* __restrict__ qt, const unsigned char* __restrict__ kv8,
    const ushort* __restrict__ attr_p, const int* __restrict__ src_p,
    const int* __restrict__ ptr, const int* __restrict__ order,
    float* __restrict__ mbuf, ushort* __restrict__ s_b) {
  const int slot = blockIdx.x * 4 + (threadIdx.x >> 6);
  if (slot >= NN) return;
  const int n = order[slot];
  const int l = threadIdx.x & 63;
  const int i = l & 7;
  float qf[16];
  {
    H8 q0, q1;
    const ushort* qr = qt + (size_t)n * 1536 + l * 16;
    q0.s = *(const short8*)qr;
    q1.s = *(const short8*)(qr + 8);
#pragma unroll
    for (int j = 0; j < 8; ++j) { qf[j] = h2f((ushort)q0.s[j]); qf[8 + j] = h2f((ushort)q1.s[j]); }
  }
  H8 tv;
  tv.s = *(const short8*)(qt + (size_t)n * 1536 + 1024 + l * 8);
  const int beg = ptr[n], end = ptr[n + 1];
  float m = -1e30f, den = 0.f;
  float acc[16] = {};
  float sa[8] = {};
  uint4 kw, vw; H8 av;
  if (beg < end) {
    int s0 = src_p[beg];
    const unsigned char* kr = kv8 + (size_t)s0 * 2048 + l * 16;
    kw = *(const uint4*)kr;
    vw = *(const uint4*)(kr + 1024);
    av.s = *(const short8*)(attr_p + (size_t)beg * 64 + i * 8);
  }
  for (int idx = beg; idx < end; ++idx) {
    uint4 ckw = kw, cvw = vw; H8 cav = av;
    int nidx = (idx + 1 < end) ? idx + 1 : idx;
    int ns = src_p[nidx];
    const unsigned char* kr = kv8 + (size_t)ns * 2048 + l * 16;
    kw = *(const uint4*)kr;
    vw = *(const uint4*)(kr + 1024);
    av.s = *(const short8*)(attr_p + (size_t)nidx * 64 + i * 8);
    float p = 0.f;
    {
      const unsigned* kws = (const unsigned*)&ckw;
#pragma unroll
      for (int j = 0; j < 4; ++j) {
        f32x2 lo = dec2<false>(kws[j]), hi = dec2<true>(kws[j]);
        p += qf[4 * j] * lo[0] + qf[4 * j + 1] * lo[1]
           + qf[4 * j + 2] * hi[0] + qf[4 * j + 3] * hi[1];
      }
    }
#pragma unroll
    for (int j = 0; j < 4; ++j) p = FDOT2(tv.h[j], cav.h[j], p);
    p += __shfl_xor(p, 1, 64);
    p += __shfl_xor(p, 2, 64);
    p += __shfl_xor(p, 4, 64);
    p *= 0.12751593061420927f;  // (1/sqrt(128)) * log2(e) -> exp2 domain
    float mn = fmaxf(m, p);
    float r = exp2f(m - mn);
    float ex = exp2f(p - mn);
    den = den * r + ex;
    {
      const unsigned* vws = (const unsigned*)&cvw;
#pragma unroll
      for (int j = 0; j < 4; ++j) {
        f32x2 lo = dec2<false>(vws[j]), hi = dec2<true>(vws[j]);
        acc[4 * j]     = acc[4 * j]     * r + ex * lo[0];
        acc[4 * j + 1] = acc[4 * j + 1] * r + ex * lo[1];
        acc[4 * j + 2] = acc[4 * j + 2] * r + ex * hi[0];
        acc[4 * j + 3] = acc[4 * j + 3] * r + ex * hi[1];
      }
    }
#pragma unroll
    for (int j = 0; j < 4; ++j) {
      sa[2 * j]     = sa[2 * j]     * r + ex * (float)cav.h[j][0];
      sa[2 * j + 1] = sa[2 * j + 1] * r + ex * (float)cav.h[j][1];
    }
    m = mn;
  }
  const float invd = den > 0.f ? 1.f / den : 0.f;
  short8 sb;
#pragma unroll
  for (int j = 0; j < 8; ++j) sb[j] = (short)f2b(sa[j] * invd);
  *(short8*)(s_b + (size_t)n * 512 + l * 8) = sb;
#pragma unroll
  for (int j = 0; j < 16; ++j) {
    float a = acc[j] * invd;
    a += __shfl_xor(a, 8, 64);
    a += __shfl_xor(a, 16, 64);
    a += __shfl_xor(a, 32, 64);
    acc[j] = a;
  }
  if (l < 8) {  // h==0 lanes, i==l
    float* mb = mbuf + (size_t)n * 128 + l * 16;
#pragma unroll
    for (int j = 0; j < 16; j += 4) {
      float4 o = make_float4(acc[j] * 0.125f, acc[j + 1] * 0.125f,
                             acc[j + 2] * 0.125f, acc[j + 3] * 0.125f);
      *(float4*)(mb + j) = o;
    }
  }
}

// ---------------- GraphNorm: atomic-free partials (8 chunks), finalize in apply ----
__global__ __launch_bounds__(256) void k_gn_partial(
    const float* __restrict__ x, const int* __restrict__ bptr,
    float* __restrict__ part) {
  const int b = blockIdx.x >> 3, chunk = blockIdx.x & 7;
  const int t = threadIdx.x;
  const int c = t & 127, half = t >> 7;
  const int beg = bptr[b], end = bptr[b + 1];
  float s = 0.f, s2 = 0.f;
  for (int n = beg + chunk * 2 + half; n < end; n += 16) {
    float v = x[(size_t)n * 128 + c];
    s += v; s2 += v * v;
  }
  __shared__ float r1[256];
  __shared__ float r2[256];
  r1[t] = s; r2[t] = s2;
  __syncthreads();
  if (half == 0) {
    part[((size_t)chunk * NB + b) * 128 + c] = r1[c] + r1[c + 128];
    part[8 * NB * 128 + ((size_t)chunk * NB + b) * 128 + c] = r2[c] + r2[c + 128];
  }
}

__global__ void k_gn_apply(const float* __restrict__ x, const int* __restrict__ batch,
                           const int* __restrict__ bptr, const float* __restrict__ part,
                           const float* __restrict__ ms, const float* __restrict__ wgt,
                           const float* __restrict__ gnb,
                           float* __restrict__ fout, ushort* __restrict__ bout) {
  int i = blockIdx.x * 256 + threadIdx.x;
  int n = i >> 7, c = i & 127;
  int b = batch[n];
  float S = 0.f, S2 = 0.f;
#pragma unroll
  for (int ch = 0; ch < 8; ++ch) {
    S  += part[((size_t)ch * NB + b) * 128 + c];
    S2 += part[8 * NB * 128 + ((size_t)ch * NB + b) * 128 + c];
  }
  float cnt = fmaxf((float)(bptr[b + 1] - bptr[b]), 1.f);
  float mean = S / cnt;
  float mm = mean * ms[c];
  float var = S2 / cnt - 2.f * mm * mean + mm * mm;
  float o = (x[i] - mm) * rsqrtf(var + 1e-5f) * wgt[c] + gnb[c];
  o = o > 0.f ? o : 0.01f * o;
  if (fout) fout[i] = o;
  if (bout) bout[i] = f2b(o);
}

extern "C" void kernel_launch(void* const* d_in, const int* in_sizes, int n_in,
                              void* d_out, int out_size, void* d_ws, size_t ws_size,
                              hipStream_t stream) {
  const float* x     = (const float*)d_in[0];
  const int*   index = (const int*)d_in[1];
  const float* attr  = (const float*)d_in[2];
  const int*   batch = (const int*)d_in[3];
  const int* srcArr = index;
  const int* dstArr = index + NE;

  char* p = (char*)d_ws;
  auto take = [&](size_t bytes) {
    char* r = p;
    p += (bytes + 255) & ~(size_t)255;
    return (void*)r;
  };
  ushort* qt_b   = (ushort*)take((size_t)NN * 1536 * 2);   // f16 [q|t]
  unsigned char* kv8 = (unsigned char*)take((size_t)NN * 2048);  // fp8 [k|v]
  ushort* s_b    = (ushort*)take((size_t)NN * 512 * 2);    // bf16
  float*  mbuf   = (float*)take((size_t)NN * 128 * 4);
  float*  hbuf   = (float*)take((size_t)NN * 128 * 4);
  ushort* xb     = (ushort*)take((size_t)NN * 128 * 2);    // bf16
  ushort* x2b    = (ushort*)take((size_t)NN * 128 * 2);    // bf16
  ushort* attr_p = (ushort*)take((size_t)NE * 64 * 2);     // f16, CSR order
  int*    src_p  = (int*)take((size_t)NE * 4);
  float*  part   = (float*)take((size_t)8 * NB * 128 * 2 * 4);
  int* csr_ptr   = (int*)take((size_t)(NN + 1) * 4);
  int* csr_cnt   = (int*)take((size_t)NN * 4);
  int* csr_eid   = (int*)take((size_t)NE * 4);
  int* nodeorder = (int*)take((size_t)NN * 4);
  int* bptrd     = (int*)take((size_t)(NB + 1) * 4);
  ushort* WtAll[2]; ushort* Wtsk[2]; ushort* W2t[2];
  float* biasAll[2];
  for (int L = 0; L < 2; ++L) {
    WtAll[L]   = (ushort*)take((size_t)3584 * 128 * 2);  // [q|k|v|t] rows, bf16
    Wtsk[L]    = (ushort*)take((size_t)128 * 128 * 2);
    W2t[L]     = (ushort*)take((size_t)128 * 512 * 2);
    biasAll[L] = (float*)take((size_t)3584 * 4);
  }

  // ---- CSR over dst + LPT order + batch boundaries + conversions ----
  const int nb_histo = (NE + 255) / 256;
  hipMemsetAsync(csr_cnt, 0, NN * 4, stream);
  k_histo_bptr<<<nb_histo + 1, 256, 0, stream>>>(dstArr, csr_cnt, batch, bptrd, nb_histo);
  k_scan_sort<<<1, 256, 0, stream>>>(csr_cnt, csr_ptr, nodeorder);
  k_scatter<<<nb_histo, 256, 0, stream>>>(dstArr, csr_ptr, csr_cnt, csr_eid);
  k_permattr_cvt<<<(NE * 16 + NN * 128 / 4 + 255) / 256, 256, 0, stream>>>(
      csr_eid, srcArr, attr, src_p, attr_p, x, xb);

  // ---- weight prep (all matrices, both layers) ----
  WtPrep WP;
  PrepPtrs PP;
  for (int L = 0; L < 2; ++L) {
    const float* Wq  = (const float*)d_in[4 + L * 12 + 0];
    const float* bq  = (const float*)d_in[4 + L * 12 + 1];
    const float* Wk  = (const float*)d_in[4 + L * 12 + 2];
    const float* bk  = (const float*)d_in[4 + L * 12 + 3];
    const float* Wv  = (const float*)d_in[4 + L * 12 + 4];
    const float* bv  = (const float*)d_in[4 + L * 12 + 5];
    const float* We  = (const float*)d_in[4 + L * 12 + 6];
    const float* Wsk = (const float*)d_in[4 + L * 12 + 7];
    WP.W[L * 4 + 0] = Wq;  WP.O[L * 4 + 0] = WtAll[L];                      WP.Nc[L * 4 + 0] = 1024;
    WP.W[L * 4 + 1] = Wk;  WP.O[L * 4 + 1] = WtAll[L] + (size_t)1024 * 128; WP.Nc[L * 4 + 1] = 1024;
    WP.W[L * 4 + 2] = Wv;  WP.O[L * 4 + 2] = WtAll[L] + (size_t)2048 * 128; WP.Nc[L * 4 + 2] = 1024;
    WP.W[L * 4 + 3] = Wsk; WP.O[L * 4 + 3] = Wtsk[L];                       WP.Nc[L * 4 + 3] = 128;
    PP.Wq[L] = Wq; PP.We[L] = We; PP.Mt[L] = WtAll[L] + (size_t)3072 * 128;
    PP.bq[L] = bq; PP.bk[L] = bk; PP.bv[L] = bv;
    PP.W2t[L] = W2t[L]; PP.biasAll[L] = biasAll[L];
  }
  k_wt_all<<<dim3(32, 4, 8), 256, 0, stream>>>(WP);
  k_mwt<<<dim3(64, 2), 256, 0, stream>>>(PP);
  k_w2t_bias<<<dim3(270, 2), 256, 0, stream>>>(PP);

  const int MT = (NN + 127) / 128;  // 79 row tiles
  for (int L = 0; L < 2; ++L) {
    const float* bsk = (const float*)d_in[4 + L * 12 + 8];
    const float* gnw = (const float*)d_in[4 + L * 12 + 9];
    const float* gnb = (const float*)d_in[4 + L * 12 + 10];
    const float* gnm = (const float*)d_in[4 + L * 12 + 11];
    const ushort* Ain = (L == 0) ? xb : x2b;

    k_gemm_qkvt<<<dim3(28, MT), 256, 0, stream>>>(Ain, WtAll[L], biasAll[L], qt_b, kv8, NN);
    k_fused<<<(NN + 3) / 4, 256, 0, stream>>>(qt_b, kv8, attr_p, src_p, csr_ptr, nodeorder, mbuf, s_b);
    k_gemm_out<<<dim3(1, MT), 256, 0, stream>>>(s_b, Ain, W2t[L], Wtsk[L], bsk, mbuf, hbuf, NN);
    k_gn_partial<<<NB * 8, 256, 0, stream>>>(hbuf, bptrd, part);
    k_gn_apply<<<NN * 128 / 256, 256, 0, stream>>>(
        hbuf, batch, bptrd, part, gnm, gnw, gnb,
        (L == 0) ? (float*)nullptr : (float*)d_out,
        (L == 0) ? x2b : (ushort*)nullptr);
  }
}

// Round 14
// 278.112 us; speedup vs baseline: 1.2165x; 1.0566x over previous
//
#include <hip/hip_runtime.h>
#include <hip/hip_bf16.h>
#include <math.h>

#define NN 10000
#define NE 100000
#define NB 32

typedef __attribute__((ext_vector_type(8))) short short8;
typedef __attribute__((ext_vector_type(4))) float f32x4;
typedef __attribute__((ext_vector_type(2))) float f32x2;
typedef _Float16 h2 __attribute__((ext_vector_type(2)));

union H8 { short8 s; h2 h[4]; };
union HU { _Float16 h; ushort u; };

__device__ inline ushort f2b(float f) {
  union { float f; unsigned u; } a; a.f = f;
  unsigned r = a.u + 0x7fff + ((a.u >> 16) & 1);
  return (ushort)(r >> 16);
}
__device__ inline float bf2f(ushort u) {
  union { unsigned u; float f; } a; a.u = ((unsigned)u) << 16;
  return a.f;
}
__device__ inline ushort f2h(float f) { HU x; x.h = (_Float16)f; return x.u; }
__device__ inline float h2f(ushort u) { HU x; x.u = u; return (float)x.h; }

// ---- fp8 e4m3 encode/decode (HW on gfx950, SW fallback) ----
__device__ inline float e4m3_sw(unsigned b) {
  unsigned s = b & 0x80, e = (b >> 3) & 15, m = b & 7;
  float v = (e == 0) ? (float)m * (1.f / 512.f) : ldexpf((float)(8 + m), (int)e - 10);
  return s ? -v : v;
}
__device__ inline unsigned f2e4m3_sw(float f) {
  unsigned s = (__float_as_uint(f) >> 24) & 0x80;
  float a = fabsf(f);
  if (a < 0.0009765625f) return s;
  if (a >= 448.f) return s | 0x7e;
  if (a < 0.015625f) {
    int q = (int)rintf(a * 512.f);
    return s | (unsigned)q;
  }
  int e2; frexpf(a, &e2);
  int sh = e2 - 4;
  int M = (int)rintf(ldexpf(a, -sh));
  if (M >= 16) { M >>= 1; sh++; }
  int E = sh + 10;
  if (E > 15) return s | 0x7e;
  return s | (unsigned)((E << 3) | (M - 8));
}

#if defined(__has_builtin)
#if __has_builtin(__builtin_amdgcn_cvt_pk_f32_fp8) && __has_builtin(__builtin_amdgcn_cvt_pk_fp8_f32)
#define HW_FP8 1
#endif
#endif

#ifdef HW_FP8
template <bool HI>
__device__ inline f32x2 dec2(unsigned w) {
  return __builtin_amdgcn_cvt_pk_f32_fp8((int)w, HI);
}
template <bool HI>
__device__ inline unsigned enc2(float a, float b, unsigned old) {
  return (unsigned)__builtin_amdgcn_cvt_pk_fp8_f32(a, b, (int)old, HI);
}
#else
template <bool HI>
__device__ inline f32x2 dec2(unsigned w) {
  unsigned x = HI ? (w >> 16) : (w & 0xffff);
  f32x2 r; r[0] = e4m3_sw(x & 0xff); r[1] = e4m3_sw((x >> 8) & 0xff);
  return r;
}
template <bool HI>
__device__ inline unsigned enc2(float a, float b, unsigned old) {
  unsigned pk = f2e4m3_sw(a) | (f2e4m3_sw(b) << 8);
  return HI ? ((old & 0xffffu) | (pk << 16)) : ((old & 0xffff0000u) | pk);
}
#endif

#if defined(__has_builtin)
#if __has_builtin(__builtin_amdgcn_fdot2)
#define FDOT2(a, b, c) __builtin_amdgcn_fdot2((a), (b), (c), false)
#endif
#endif
#ifndef FDOT2
#define FDOT2(a, b, c) ((c) + (float)(a)[0] * (float)(b)[0] + (float)(a)[1] * (float)(b)[1])
#endif

#define GLDS(g, l)                                                        \
  __builtin_amdgcn_global_load_lds(                                       \
      (const __attribute__((address_space(1))) unsigned*)(g),             \
      (__attribute__((address_space(3))) unsigned*)(l), 16, 0, 0)

// ------- qkvt GEMM: A[M,128](bf16) @ Bt[3584,128]^T + bias ->
//         cols [0,1024) f16->qt, [1024,3072) fp8->kv8, [3072,3584) f16->qt(+1024-2048)
__global__ __launch_bounds__(256) void k_gemm_qkvt(
    const ushort* __restrict__ Abf, const ushort* __restrict__ Bt,
    const float* __restrict__ bias, ushort* __restrict__ qt,
    unsigned char* __restrict__ kv8, int M) {
  __shared__ ushort As[128 * 128];
  __shared__ ushort Bs[128 * 128];
  const int tid = threadIdx.x;
  const int l = tid & 63, w = tid >> 6;
  const int wm = w & 1, wn = w >> 1;
  const int row0 = blockIdx.y * 128, col0 = blockIdx.x * 128;
#pragma unroll
  for (int i = 0; i < 8; ++i) {
    int idx = i * 256 + tid;
    int r = idx >> 4, cb = (idx & 15) << 4;
    int scb = cb ^ ((r & 7) << 4);   // pre-swizzled source, linear LDS dest
    GLDS((const char*)Abf + (size_t)(row0 + r) * 256 + scb, (char*)As + idx * 16);
    GLDS((const char*)Bt + (size_t)(col0 + r) * 256 + scb, (char*)Bs + idx * 16);
  }
  __syncthreads();
  f32x4 acc[4][4] = {};
#pragma unroll
  for (int kk = 0; kk < 4; ++kk) {
    short8 af[4], bf[4];
#pragma unroll
    for (int fm = 0; fm < 4; ++fm) {
      int r = wm * 64 + fm * 16 + (l & 15);
      int cb = (kk * 64 + ((l >> 4) << 4)) ^ ((r & 7) << 4);
      af[fm] = *(const short8*)((const char*)As + r * 256 + cb);
    }
#pragma unroll
    for (int fn = 0; fn < 4; ++fn) {
      int r = wn * 64 + fn * 16 + (l & 15);
      int cb = (kk * 64 + ((l >> 4) << 4)) ^ ((r & 7) << 4);
      bf[fn] = *(const short8*)((const char*)Bs + r * 256 + cb);
    }
#pragma unroll
    for (int fm = 0; fm < 4; ++fm)
#pragma unroll
      for (int fn = 0; fn < 4; ++fn)
        acc[fm][fn] = __builtin_amdgcn_mfma_f32_16x16x32_bf16(af[fm], bf[fn], acc[fm][fn], 0, 0, 0);
  }
  // stage acc (f16) into As, swizzled
  __syncthreads();
#pragma unroll
  for (int fm = 0; fm < 4; ++fm) {
    int rloc = wm * 64 + fm * 16 + ((l >> 4) << 2);
#pragma unroll
    for (int fn = 0; fn < 4; ++fn) {
      int cbyte = (wn * 64 + fn * 16 + (l & 15)) * 2;
#pragma unroll
      for (int b = 0; b < 4; ++b) {
        int r = rloc + b;
        *(ushort*)((char*)As + r * 256 + (cbyte ^ ((r & 7) << 4))) = f2h(acc[fm][fn][b]);
      }
    }
  }
  __syncthreads();
  const bool isf16 = (col0 < 1024) || (col0 >= 3072);
#pragma unroll
  for (int it = 0; it < 8; ++it) {
    int idx = it * 256 + tid;
    int r = idx >> 4, cb16 = (idx & 15) << 4;
    int gr = row0 + r;
    if (gr >= M) continue;
    short8 v = *(const short8*)((const char*)As + r * 256 + (cb16 ^ ((r & 7) << 4)));
    int co = cb16 >> 1;  // col offset within 128, multiple of 8
    if (isf16) {
      int qc0 = ((col0 < 1024) ? col0 : (col0 - 2048)) + co;
      short8 o;
#pragma unroll
      for (int j = 0; j < 8; ++j) o[j] = (short)f2h(h2f((ushort)v[j]) + bias[col0 + co + j]);
      *(short8*)(qt + (size_t)gr * 1536 + qc0) = o;
    } else {
      float f[8];
#pragma unroll
      for (int j = 0; j < 8; ++j) f[j] = h2f((ushort)v[j]) + bias[col0 + co + j];
      unsigned w0 = 0, w1 = 0;
      w0 = enc2<false>(f[0], f[1], w0);
      w0 = enc2<true>(f[2], f[3], w0);
      w1 = enc2<false>(f[4], f[5], w1);
      w1 = enc2<true>(f[6], f[7], w1);
      uint2 st; st.x = w0; st.y = w1;
      *(uint2*)(kv8 + (size_t)gr * 2048 + (col0 - 1024) + co) = st;
    }
  }
}

// ------- fused output GEMM + GraphNorm partial sums:
// hbuf[M,128] = s_b@W2t^T + x@Wsk^T + bsk + mbuf; per-batch col sums -> gs/gs2 (atomic).
// Each block owns ALL 128 cols of its 128 rows, so GN partials computed from the LDS tile.
__global__ __launch_bounds__(256) void k_gemm_out(
    const ushort* __restrict__ s_b, const ushort* __restrict__ xin,
    const ushort* __restrict__ W2t, const ushort* __restrict__ Wsk,
    const float* __restrict__ bsk, const float* __restrict__ mbuf,
    const int* __restrict__ batch, const int* __restrict__ bptr,
    float* __restrict__ gs, float* __restrict__ gs2,
    float* __restrict__ Cf, int M) {
  __shared__ float fsm[128 * 128];          // 64 KB: ushort staging (As|Bs) then f32 tile
  ushort* As = (ushort*)fsm;                // first 32 KB
  ushort* Bs = (ushort*)fsm + 128 * 128;    // second 32 KB
  const int tid = threadIdx.x;
  const int l = tid & 63, w = tid >> 6;
  const int wm = w & 1, wn = w >> 1;
  const int row0 = blockIdx.y * 128;
  f32x4 acc[4][4] = {};
  for (int kt = 0; kt < 5; ++kt) {
    if (kt) __syncthreads();
    const char* Ab; const char* Bb; size_t arb, brb; int ko;
    if (kt < 4) { Ab = (const char*)s_b; arb = 1024; Bb = (const char*)W2t; brb = 1024; ko = kt * 256; }
    else        { Ab = (const char*)xin; arb = 256;  Bb = (const char*)Wsk; brb = 256;  ko = 0; }
#pragma unroll
    for (int i = 0; i < 8; ++i) {
      int idx = i * 256 + tid;
      int r = idx >> 4, cb = (idx & 15) << 4;
      int scb = cb ^ ((r & 7) << 4);
      GLDS(Ab + (size_t)(row0 + r) * arb + ko + scb, (char*)As + idx * 16);
      GLDS(Bb + (size_t)r * brb + ko + scb, (char*)Bs + idx * 16);
    }
    __syncthreads();
#pragma unroll
    for (int kk = 0; kk < 4; ++kk) {
      short8 af[4], bf[4];
#pragma unroll
      for (int fm = 0; fm < 4; ++fm) {
        int r = wm * 64 + fm * 16 + (l & 15);
        int cb = (kk * 64 + ((l >> 4) << 4)) ^ ((r & 7) << 4);
        af[fm] = *(const short8*)((const char*)As + r * 256 + cb);
      }
#pragma unroll
      for (int fn = 0; fn < 4; ++fn) {
        int r = wn * 64 + fn * 16 + (l & 15);
        int cb = (kk * 64 + ((l >> 4) << 4)) ^ ((r & 7) << 4);
        bf[fn] = *(const short8*)((const char*)Bs + r * 256 + cb);
      }
#pragma unroll
      for (int fm = 0; fm < 4; ++fm)
#pragma unroll
        for (int fn = 0; fn < 4; ++fn)
          acc[fm][fn] = __builtin_amdgcn_mfma_f32_16x16x32_bf16(af[fm], bf[fn], acc[fm][fn], 0, 0, 0);
    }
  }
  __syncthreads();  // all LDS reads done before tile overwrite
#pragma unroll
  for (int fm = 0; fm < 4; ++fm) {
    int rloc0 = wm * 64 + fm * 16 + ((l >> 4) << 2);
#pragma unroll
    for (int fn = 0; fn < 4; ++fn) {
      int col = wn * 64 + fn * 16 + (l & 15);
      float bb = bsk[col];
#pragma unroll
      for (int b = 0; b < 4; ++b) {
        int rloc = rloc0 + b;
        int rr = row0 + rloc;
        float val = 0.f;
        if (rr < M) {
          val = acc[fm][fn][b] + bb + mbuf[(size_t)rr * 128 + col];
          Cf[(size_t)rr * 128 + col] = val;
        }
        fsm[rloc * 128 + col] = val;
      }
    }
  }
  __syncthreads();
  // GraphNorm partial sums per batch segment in this row block
  const int c = tid & 127, half = tid >> 7;
  const int lastr = min(row0 + 127, M - 1);
  const int bmin = batch[row0 < M ? row0 : M - 1];
  const int bmax = batch[lastr];
  for (int b = bmin; b <= bmax; ++b) {
    int rlo = max(bptr[b], row0) - row0;
    int rhi = min(bptr[b + 1], min(row0 + 128, M)) - row0;
    float s = 0.f, s2 = 0.f;
    for (int r = rlo + half; r < rhi; r += 2) {
      float v = fsm[r * 128 + c];
      s += v; s2 += v * v;
    }
    if (rhi > rlo) {
      atomicAdd(&gs[b * 128 + c], s);
      atomicAdd(&gs2[b * 128 + c], s2);
    }
  }
}

// ---------------- weight prep ----------------
struct WtPrep { const float* W[8]; ushort* O[8]; int Nc[8]; };
__global__ void k_wt_all(WtPrep P) {
  const int z = blockIdx.z;
  const int Nc = P.Nc[z];
  if ((int)blockIdx.x * 32 >= Nc) return;
  const float* __restrict__ W = P.W[z];
  ushort* __restrict__ Wt = P.O[z];
  __shared__ float tile[32][33];
  const int t = threadIdx.x, lx = t & 31, ly = t >> 5;
  const int bx = blockIdx.x, by = blockIdx.y;
#pragma unroll
  for (int i = 0; i < 4; ++i)
    tile[ly + i * 8][lx] = W[(by * 32 + ly + i * 8) * Nc + bx * 32 + lx];
  __syncthreads();
#pragma unroll
  for (int i = 0; i < 4; ++i)
    Wt[(size_t)(bx * 32 + ly + i * 8) * 128 + by * 32 + lx] = f2b(tile[lx][ly + i * 8]);
}

struct PrepPtrs {
  const float* Wq[2]; const float* We[2]; ushort* Mt[2];
  const float* bq[2]; const float* bk[2]; const float* bv[2];
  ushort* W2t[2]; float* biasAll[2];
};

// Mt[(h*64+d)*128 + p] = bf16( sum_c Wq[p,h*128+c] * We[d,h*128+c] );  grid (64, 2)
__global__ __launch_bounds__(256) void k_mwt(PrepPtrs P) {
  const int L = blockIdx.y;
  const float* __restrict__ Wq = P.Wq[L];
  const float* __restrict__ We = P.We[L];
  ushort* __restrict__ Mt = P.Mt[L];
  const int h = blockIdx.x >> 3, pt = blockIdx.x & 7;
  const int t = threadIdx.x;
  __shared__ float Wes[64][129];
  __shared__ float Wqs[16][129];
#pragma unroll
  for (int i = 0; i < 32; ++i) {
    int idx = i * 256 + t;
    Wes[idx >> 7][idx & 127] = We[(idx >> 7) * 1024 + h * 128 + (idx & 127)];
  }
#pragma unroll
  for (int i = 0; i < 8; ++i) {
    int idx = i * 256 + t;
    Wqs[idx >> 7][idx & 127] = Wq[(pt * 16 + (idx >> 7)) * 1024 + h * 128 + (idx & 127)];
  }
  __syncthreads();
#pragma unroll
  for (int i = 0; i < 4; ++i) {
    int o = i * 256 + t;
    int d = o & 63, p = o >> 6;
    float s = 0.f;
#pragma unroll 8
    for (int c = 0; c < 128; ++c) s += Wqs[p][c] * Wes[d][c];
    Mt[(size_t)(h * 64 + d) * 128 + pt * 16 + p] = f2b(s);
  }
}

// merged: o<65536 -> W2t[c*512+h*64+d] = bf16(We[d,h*128+c]/8); else biasAll; grid (270, 2)
__global__ void k_w2t_bias(PrepPtrs P) {
  const int L = blockIdx.y;
  int o = blockIdx.x * 256 + threadIdx.x;
  if (o < 128 * 512) {
    int c = o >> 9, hd = o & 511;
    int hh = hd >> 6, d = hd & 63;
    P.W2t[L][o] = f2b(P.We[L][d * 1024 + hh * 128 + c] * 0.125f);
  } else {
    int o2 = o - 128 * 512;
    if (o2 >= 3584) return;
    if (o2 < 1024) P.biasAll[L][o2] = P.bq[L][o2];
    else if (o2 < 2048) P.biasAll[L][o2] = P.bk[L][o2 - 1024];
    else if (o2 < 3072) P.biasAll[L][o2] = P.bv[L][o2 - 2048];
    else {
      int hd = o2 - 3072;
      int h = hd >> 6, d = hd & 63;
      float s = 0.f;
      for (int c = 0; c < 128; ++c) s += P.bq[L][h * 128 + c] * P.We[L][d * 1024 + h * 128 + c];
      P.biasAll[L][o2] = s;
    }
  }
}

// ---------------- CSR build over dst (+ batch boundaries merged) ----------------
__global__ void k_histo_bptr(const int* __restrict__ dst, int* __restrict__ cnt,
                             const int* __restrict__ batch, int* __restrict__ bptr,
                             int nb_histo) {
  if ((int)blockIdx.x < nb_histo) {
    int e = blockIdx.x * 256 + threadIdx.x;
    if (e < NE) atomicAdd(&cnt[dst[e]], 1);
  } else {
    int b = threadIdx.x;
    if (b > NB) return;
    int lo = 0, hi = NN;
    while (lo < hi) { int mid = (lo + hi) >> 1; if (batch[mid] < b) lo = mid + 1; else hi = mid; }
    bptr[b] = lo;
  }
}

// merged scan + LPT counting sort (single block, 256 threads)
__global__ __launch_bounds__(256) void k_scan_sort(const int* __restrict__ cnt,
                                                   int* __restrict__ ptr,
                                                   int* __restrict__ order) {
  __shared__ int tsum[256];
  __shared__ int hist[256];
  __shared__ int offs[256];
  __shared__ int fill[256];
  __shared__ int sc[256];
  const int t = threadIdx.x;
  const int base = t * 40;
  int s = 0;
  for (int i = 0; i < 40; ++i) { int idx = base + i; if (idx < NN) s += cnt[idx]; }
  tsum[t] = s;
  hist[t] = 0;
  __syncthreads();
  for (int off = 1; off < 256; off <<= 1) {
    int v = (t >= off) ? tsum[t - off] : 0;
    __syncthreads();
    tsum[t] += v;
    __syncthreads();
  }
  int run = (t == 0) ? 0 : tsum[t - 1];
  for (int i = 0; i < 40; ++i) {
    int idx = base + i;
    if (idx < NN) { ptr[idx] = run; run += cnt[idx]; }
  }
  if (t == 255) ptr[NN] = tsum[255];
  for (int n = t; n < NN; n += 256) {
    int d = min(cnt[n], 255);
    atomicAdd(&hist[d], 1);
  }
  __syncthreads();
  const int rd = 255 - t;
  int v = hist[rd];
  sc[t] = v;
  __syncthreads();
  for (int off = 1; off < 256; off <<= 1) {
    int u = (t >= off) ? sc[t - off] : 0;
    __syncthreads();
    sc[t] += u;
    __syncthreads();
  }
  offs[rd] = sc[t] - v;
  fill[rd] = 0;
  __syncthreads();
  for (int n = t; n < NN; n += 256) {
    int d = min(cnt[n], 255);
    int pos = offs[d] + atomicAdd(&fill[d], 1);
    order[pos] = n;
  }
}

// countdown scatter: cnt[d] holds degree after histo; no second memset needed
__global__ void k_scatter(const int* __restrict__ dst, const int* __restrict__ ptr,
                          int* __restrict__ cnt, int* __restrict__ eid) {
  int e = blockIdx.x * 256 + threadIdx.x;
  if (e < NE) {
    int d = dst[e];
    int pos = ptr[d] + atomicSub(&cnt[d], 1) - 1;
    eid[pos] = e;
  }
}

// merged: permute attr + src into CSR order, x f32->bf16, zero GN stat buffers
__global__ void k_permattr_cvt(const int* __restrict__ eid, const int* __restrict__ src,
                               const float* __restrict__ attr, int* __restrict__ src_p,
                               ushort* __restrict__ attr_p,
                               const float* __restrict__ x, ushort* __restrict__ xb,
                               float* __restrict__ gsAll) {
  int i = blockIdx.x * 256 + threadIdx.x;
  if (i < NE * 16) {
    int idx = i >> 4, part = i & 15;
    int e = eid[idx];
    if (part == 0) src_p[idx] = src[e];
    float4 v = *(const float4*)(attr + (size_t)e * 64 + part * 4);
    ushort4 o;
    o.x = f2h(v.x); o.y = f2h(v.y); o.z = f2h(v.z); o.w = f2h(v.w);
    *(ushort4*)(attr_p + (size_t)idx * 64 + part * 4) = o;
  } else if (i < NE * 16 + NN * 128 / 4) {
    int j = i - NE * 16;
    float4 v = *(const float4*)(x + j * 4);
    ushort4 o;
    o.x = f2b(v.x); o.y = f2b(v.y); o.z = f2b(v.z); o.w = f2b(v.w);
    *(ushort4*)(xb + j * 4) = o;
  } else {
    int j = i - NE * 16 - NN * 128 / 4;
    if (j < 2 * 2 * NB * 128) gsAll[j] = 0.f;
  }
}

// ---------------- fused attention: 4 independent waves per block (LPT), fp8 k/v ----
// NOTE: no min-waves clamp (R9 spill); 1-deep prefetch only (R11 VGPR cliff).
__global__ __launch_bounds__(256) void k_fused(
    const ushort* __restrict__ qt, const unsigned char* __restrict__ kv8,
    const ushort* __restrict__ attr_p, const int* __restrict__ src_p,
    const int* __restrict__ ptr, const int* __restrict__ order,
    float* __restrict__ mbuf, ushort* __restrict__ s_b) {
  const int slot = blockIdx.x * 4 + (threadIdx.x >> 6);
  if (slot >= NN) return;
  const int n = order[slot];
  const int l = threadIdx.x & 63;
  const int i = l & 7;
  float qf[16];
  {
    H8 q0, q1;
    const ushort* qr = qt + (size_t)n * 1536 + l * 16;
    q0.s = *(const short8*)qr;
    q1.s = *(const short8*)(qr + 8);
#pragma unroll
    for (int j = 0; j < 8; ++j) { qf[j] = h2f((ushort)q0.s[j]); qf[8 + j] = h2f((ushort)q1.s[j]); }
  }
  H8 tv;
  tv.s = *(const short8*)(qt + (size_t)n * 1536 + 1024 + l * 8);
  const int beg = ptr[n], end = ptr[n + 1];
  float m = -1e30f, den = 0.f;
  float acc[16] = {};
  float sa[8] = {};
  uint4 kw, vw; H8 av;
  if (beg < end) {
    int s0 = src_p[beg];
    const unsigned char* kr = kv8 + (size_t)s0 * 2048 + l * 16;
    kw = *(const uint4*)kr;
    vw = *(const uint4*)(kr + 1024);
    av.s = *(const short8*)(attr_p + (size_t)beg * 64 + i * 8);
  }
  for (int idx = beg; idx < end; ++idx) {
    uint4 ckw = kw, cvw = vw; H8 cav = av;
    int nidx = (idx + 1 < end) ? idx + 1 : idx;
    int ns = src_p[nidx];
    const unsigned char* kr = kv8 + (size_t)ns * 2048 + l * 16;
    kw = *(const uint4*)kr;
    vw = *(const uint4*)(kr + 1024);
    av.s = *(const short8*)(attr_p + (size_t)nidx * 64 + i * 8);
    float p = 0.f;
    {
      const unsigned* kws = (const unsigned*)&ckw;
#pragma unroll
      for (int j = 0; j < 4; ++j) {
        f32x2 lo = dec2<false>(kws[j]), hi = dec2<true>(kws[j]);
        p += qf[4 * j] * lo[0] + qf[4 * j + 1] * lo[1]
           + qf[4 * j + 2] * hi[0] + qf[4 * j + 3] * hi[1];
      }
    }
#pragma unroll
    for (int j = 0; j < 4; ++j) p = FDOT2(tv.h[j], cav.h[j], p);
    p += __shfl_xor(p, 1, 64);
    p += __shfl_xor(p, 2, 64);
    p += __shfl_xor(p, 4, 64);
    p *= 0.12751593061420927f;  // (1/sqrt(128)) * log2(e) -> exp2 domain
    float mn = fmaxf(m, p);
    float r = exp2f(m - mn);
    float ex = exp2f(p - mn);
    den = den * r + ex;
    {
      const unsigned* vws = (const unsigned*)&cvw;
#pragma unroll
      for (int j = 0; j < 4; ++j) {
        f32x2 lo = dec2<false>(vws[j]), hi = dec2<true>(vws[j]);
        acc[4 * j]     = acc[4 * j]     * r + ex * lo[0];
        acc[4 * j + 1] = acc[4 * j + 1] * r + ex * lo[1];
        acc[4 * j + 2] = acc[4 * j + 2] * r + ex * hi[0];
        acc[4 * j + 3] = acc[4 * j + 3] * r + ex * hi[1];
      }
    }
#pragma unroll
    for (int j = 0; j < 4; ++j) {
      sa[2 * j]     = sa[2 * j]     * r + ex * (float)cav.h[j][0];
      sa[2 * j + 1] = sa[2 * j + 1] * r + ex * (float)cav.h[j][1];
    }
    m = mn;
  }
  const float invd = den > 0.f ? 1.f / den : 0.f;
  short8 sb;
#pragma unroll
  for (int j = 0; j < 8; ++j) sb[j] = (short)f2b(sa[j] * invd);
  *(short8*)(s_b + (size_t)n * 512 + l * 8) = sb;
#pragma unroll
  for (int j = 0; j < 16; ++j) {
    float a = acc[j] * invd;
    a += __shfl_xor(a, 8, 64);
    a += __shfl_xor(a, 16, 64);
    a += __shfl_xor(a, 32, 64);
    acc[j] = a;
  }
  if (l < 8) {  // h==0 lanes, i==l
    float* mb = mbuf + (size_t)n * 128 + l * 16;
#pragma unroll
    for (int j = 0; j < 16; j += 4) {
      float4 o = make_float4(acc[j] * 0.125f, acc[j + 1] * 0.125f,
                             acc[j + 2] * 0.125f, acc[j + 3] * 0.125f);
      *(float4*)(mb + j) = o;
    }
  }
}

// ---------------- GraphNorm apply (stats precomputed by k_gemm_out) ----------------
__global__ void k_gn_apply(const float* __restrict__ x, const int* __restrict__ batch,
                           const int* __restrict__ bptr,
                           const float* __restrict__ gs, const float* __restrict__ gs2,
                           const float* __restrict__ ms, const float* __restrict__ wgt,
                           const float* __restrict__ gnb,
                           float* __restrict__ fout, ushort* __restrict__ bout) {
  int i = blockIdx.x * 256 + threadIdx.x;
  int n = i >> 7, c = i & 127;
  int b = batch[n];
  float cnt = fmaxf((float)(bptr[b + 1] - bptr[b]), 1.f);
  float mean = gs[b * 128 + c] / cnt;
  float mm = mean * ms[c];
  float var = gs2[b * 128 + c] / cnt - 2.f * mm * mean + mm * mm;
  float o = (x[i] - mm) * rsqrtf(var + 1e-5f) * wgt[c] + gnb[c];
  o = o > 0.f ? o : 0.01f * o;
  if (fout) fout[i] = o;
  if (bout) bout[i] = f2b(o);
}

extern "C" void kernel_launch(void* const* d_in, const int* in_sizes, int n_in,
                              void* d_out, int out_size, void* d_ws, size_t ws_size,
                              hipStream_t stream) {
  const float* x     = (const float*)d_in[0];
  const int*   index = (const int*)d_in[1];
  const float* attr  = (const float*)d_in[2];
  const int*   batch = (const int*)d_in[3];
  const int* srcArr = index;
  const int* dstArr = index + NE;

  char* p = (char*)d_ws;
  auto take = [&](size_t bytes) {
    char* r = p;
    p += (bytes + 255) & ~(size_t)255;
    return (void*)r;
  };
  ushort* qt_b   = (ushort*)take((size_t)NN * 1536 * 2);   // f16 [q|t]
  unsigned char* kv8 = (unsigned char*)take((size_t)NN * 2048);  // fp8 [k|v]
  ushort* s_b    = (ushort*)take((size_t)NN * 512 * 2);    // bf16
  float*  mbuf   = (float*)take((size_t)NN * 128 * 4);
  float*  hbuf   = (float*)take((size_t)NN * 128 * 4);
  ushort* xb     = (ushort*)take((size_t)NN * 128 * 2);    // bf16
  ushort* x2b    = (ushort*)take((size_t)NN * 128 * 2);    // bf16
  ushort* attr_p = (ushort*)take((size_t)NE * 64 * 2);     // f16, CSR order
  int*    src_p  = (int*)take((size_t)NE * 4);
  float*  gsAll  = (float*)take((size_t)2 * 2 * NB * 128 * 4);  // per-layer gs|gs2
  int* csr_ptr   = (int*)take((size_t)(NN + 1) * 4);
  int* csr_cnt   = (int*)take((size_t)NN * 4);
  int* csr_eid   = (int*)take((size_t)NE * 4);
  int* nodeorder = (int*)take((size_t)NN * 4);
  int* bptrd     = (int*)take((size_t)(NB + 1) * 4);
  ushort* WtAll[2]; ushort* Wtsk[2]; ushort* W2t[2];
  float* biasAll[2];
  for (int L = 0; L < 2; ++L) {
    WtAll[L]   = (ushort*)take((size_t)3584 * 128 * 2);  // [q|k|v|t] rows, bf16
    Wtsk[L]    = (ushort*)take((size_t)128 * 128 * 2);
    W2t[L]     = (ushort*)take((size_t)128 * 512 * 2);
    biasAll[L] = (float*)take((size_t)3584 * 4);
  }

  // ---- CSR over dst + LPT order + batch boundaries + conversions ----
  const int nb_histo = (NE + 255) / 256;
  hipMemsetAsync(csr_cnt, 0, NN * 4, stream);
  k_histo_bptr<<<nb_histo + 1, 256, 0, stream>>>(dstArr, csr_cnt, batch, bptrd, nb_histo);
  k_scan_sort<<<1, 256, 0, stream>>>(csr_cnt, csr_ptr, nodeorder);
  k_scatter<<<nb_histo, 256, 0, stream>>>(dstArr, csr_ptr, csr_cnt, csr_eid);
  k_permattr_cvt<<<(NE * 16 + NN * 128 / 4 + 2 * 2 * NB * 128 + 255) / 256, 256, 0, stream>>>(
      csr_eid, srcArr, attr, src_p, attr_p, x, xb, gsAll);

  // ---- weight prep (all matrices, both layers) ----
  WtPrep WP;
  PrepPtrs PP;
  for (int L = 0; L < 2; ++L) {
    const float* Wq  = (const float*)d_in[4 + L * 12 + 0];
    const float* bq  = (const float*)d_in[4 + L * 12 + 1];
    const float* Wk  = (const float*)d_in[4 + L * 12 + 2];
    const float* bk  = (const float*)d_in[4 + L * 12 + 3];
    const float* Wv  = (const float*)d_in[4 + L * 12 + 4];
    const float* bv  = (const float*)d_in[4 + L * 12 + 5];
    const float* We  = (const float*)d_in[4 + L * 12 + 6];
    const float* Wsk = (const float*)d_in[4 + L * 12 + 7];
    WP.W[L * 4 + 0] = Wq;  WP.O[L * 4 + 0] = WtAll[L];                      WP.Nc[L * 4 + 0] = 1024;
    WP.W[L * 4 + 1] = Wk;  WP.O[L * 4 + 1] = WtAll[L] + (size_t)1024 * 128; WP.Nc[L * 4 + 1] = 1024;
    WP.W[L * 4 + 2] = Wv;  WP.O[L * 4 + 2] = WtAll[L] + (size_t)2048 * 128; WP.Nc[L * 4 + 2] = 1024;
    WP.W[L * 4 + 3] = Wsk; WP.O[L * 4 + 3] = Wtsk[L];                       WP.Nc[L * 4 + 3] = 128;
    PP.Wq[L] = Wq; PP.We[L] = We; PP.Mt[L] = WtAll[L] + (size_t)3072 * 128;
    PP.bq[L] = bq; PP.bk[L] = bk; PP.bv[L] = bv;
    PP.W2t[L] = W2t[L]; PP.biasAll[L] = biasAll[L];
  }
  k_wt_all<<<dim3(32, 4, 8), 256, 0, stream>>>(WP);
  k_mwt<<<dim3(64, 2), 256, 0, stream>>>(PP);
  k_w2t_bias<<<dim3(270, 2), 256, 0, stream>>>(PP);

  const int MT = (NN + 127) / 128;  // 79 row tiles
  for (int L = 0; L < 2; ++L) {
    const float* bsk = (const float*)d_in[4 + L * 12 + 8];
    const float* gnw = (const float*)d_in[4 + L * 12 + 9];
    const float* gnb = (const float*)d_in[4 + L * 12 + 10];
    const float* gnm = (const float*)d_in[4 + L * 12 + 11];
    const ushort* Ain = (L == 0) ? xb : x2b;
    float* gs  = gsAll + (size_t)L * 2 * NB * 128;
    float* gs2 = gs + NB * 128;

    k_gemm_qkvt<<<dim3(28, MT), 256, 0, stream>>>(Ain, WtAll[L], biasAll[L], qt_b, kv8, NN);
    k_fused<<<(NN + 3) / 4, 256, 0, stream>>>(qt_b, kv8, attr_p, src_p, csr_ptr, nodeorder, mbuf, s_b);
    k_gemm_out<<<dim3(1, MT), 256, 0, stream>>>(
        s_b, Ain, W2t[L], Wtsk[L], bsk, mbuf, batch, bptrd, gs, gs2, hbuf, NN);
    k_gn_apply<<<NN * 128 / 256, 256, 0, stream>>>(
        hbuf, batch, bptrd, gs, gs2, gnm, gnw, gnb,
        (L == 0) ? (float*)nullptr : (float*)d_out,
        (L == 0) ? x2b : (ushort*)nullptr);
  }
}

// Round 15
// 263.901 us; speedup vs baseline: 1.2820x; 1.0538x over previous
//
#include <hip/hip_runtime.h>
#include <hip/hip_bf16.h>
#include <math.h>

#define NN 10000
#define NE 100000
#define NB 32

typedef __attribute__((ext_vector_type(8))) short short8;
typedef __attribute__((ext_vector_type(4))) float f32x4;
typedef __attribute__((ext_vector_type(2))) float f32x2;
typedef _Float16 h2 __attribute__((ext_vector_type(2)));

union H8 { short8 s; h2 h[4]; };
union HU { _Float16 h; ushort u; };

__device__ inline ushort f2b(float f) {
  union { float f; unsigned u; } a; a.f = f;
  unsigned r = a.u + 0x7fff + ((a.u >> 16) & 1);
  return (ushort)(r >> 16);
}
__device__ inline float bf2f(ushort u) {
  union { unsigned u; float f; } a; a.u = ((unsigned)u) << 16;
  return a.f;
}
__device__ inline ushort f2h(float f) { HU x; x.h = (_Float16)f; return x.u; }
__device__ inline float h2f(ushort u) { HU x; x.u = u; return (float)x.h; }

// ---- fp8 e4m3 encode/decode (HW on gfx950, SW fallback) ----
__device__ inline float e4m3_sw(unsigned b) {
  unsigned s = b & 0x80, e = (b >> 3) & 15, m = b & 7;
  float v = (e == 0) ? (float)m * (1.f / 512.f) : ldexpf((float)(8 + m), (int)e - 10);
  return s ? -v : v;
}
__device__ inline unsigned f2e4m3_sw(float f) {
  unsigned s = (__float_as_uint(f) >> 24) & 0x80;
  float a = fabsf(f);
  if (a < 0.0009765625f) return s;
  if (a >= 448.f) return s | 0x7e;
  if (a < 0.015625f) {
    int q = (int)rintf(a * 512.f);
    return s | (unsigned)q;
  }
  int e2; frexpf(a, &e2);
  int sh = e2 - 4;
  int M = (int)rintf(ldexpf(a, -sh));
  if (M >= 16) { M >>= 1; sh++; }
  int E = sh + 10;
  if (E > 15) return s | 0x7e;
  return s | (unsigned)((E << 3) | (M - 8));
}

#if defined(__has_builtin)
#if __has_builtin(__builtin_amdgcn_cvt_pk_f32_fp8) && __has_builtin(__builtin_amdgcn_cvt_pk_fp8_f32)
#define HW_FP8 1
#endif
#endif

#ifdef HW_FP8
template <bool HI>
__device__ inline f32x2 dec2(unsigned w) {
  return __builtin_amdgcn_cvt_pk_f32_fp8((int)w, HI);
}
template <bool HI>
__device__ inline unsigned enc2(float a, float b, unsigned old) {
  return (unsigned)__builtin_amdgcn_cvt_pk_fp8_f32(a, b, (int)old, HI);
}
#else
template <bool HI>
__device__ inline f32x2 dec2(unsigned w) {
  unsigned x = HI ? (w >> 16) : (w & 0xffff);
  f32x2 r; r[0] = e4m3_sw(x & 0xff); r[1] = e4m3_sw((x >> 8) & 0xff);
  return r;
}
template <bool HI>
__device__ inline unsigned enc2(float a, float b, unsigned old) {
  unsigned pk = f2e4m3_sw(a) | (f2e4m3_sw(b) << 8);
  return HI ? ((old & 0xffffu) | (pk << 16)) : ((old & 0xffff0000u) | pk);
}
#endif

#if defined(__has_builtin)
#if __has_builtin(__builtin_amdgcn_fdot2)
#define FDOT2(a, b, c) __builtin_amdgcn_fdot2((a), (b), (c), false)
#endif
#endif
#ifndef FDOT2
#define FDOT2(a, b, c) ((c) + (float)(a)[0] * (float)(b)[0] + (float)(a)[1] * (float)(b)[1])
#endif

#define GLDS(g, l)                                                        \
  __builtin_amdgcn_global_load_lds(                                       \
      (const __attribute__((address_space(1))) unsigned*)(g),             \
      (__attribute__((address_space(3))) unsigned*)(l), 16, 0, 0)

// ------- qkvt GEMM: A[M,128](bf16) @ Bt[3584,128]^T + bias ->
//         cols [0,1024) f16->qt, [1024,3072) fp8->kv8, [3072,3584) f16->qt(+1024-2048)
//         Bias pre-added into acc before staging (epilogue = pure copy / encode).
__global__ __launch_bounds__(256) void k_gemm_qkvt(
    const ushort* __restrict__ Abf, const ushort* __restrict__ Bt,
    const float* __restrict__ bias, ushort* __restrict__ qt,
    unsigned char* __restrict__ kv8, int M) {
  __shared__ ushort As[128 * 128];
  __shared__ ushort Bs[128 * 128];
  const int tid = threadIdx.x;
  const int l = tid & 63, w = tid >> 6;
  const int wm = w & 1, wn = w >> 1;
  const int row0 = blockIdx.y * 128, col0 = blockIdx.x * 128;
#pragma unroll
  for (int i = 0; i < 8; ++i) {
    int idx = i * 256 + tid;
    int r = idx >> 4, cb = (idx & 15) << 4;
    int scb = cb ^ ((r & 7) << 4);   // pre-swizzled source, linear LDS dest
    GLDS((const char*)Abf + (size_t)(row0 + r) * 256 + scb, (char*)As + idx * 16);
    GLDS((const char*)Bt + (size_t)(col0 + r) * 256 + scb, (char*)Bs + idx * 16);
  }
  __syncthreads();
  f32x4 acc[4][4] = {};
#pragma unroll
  for (int kk = 0; kk < 4; ++kk) {
    short8 af[4], bf[4];
#pragma unroll
    for (int fm = 0; fm < 4; ++fm) {
      int r = wm * 64 + fm * 16 + (l & 15);
      int cb = (kk * 64 + ((l >> 4) << 4)) ^ ((r & 7) << 4);
      af[fm] = *(const short8*)((const char*)As + r * 256 + cb);
    }
#pragma unroll
    for (int fn = 0; fn < 4; ++fn) {
      int r = wn * 64 + fn * 16 + (l & 15);
      int cb = (kk * 64 + ((l >> 4) << 4)) ^ ((r & 7) << 4);
      bf[fn] = *(const short8*)((const char*)Bs + r * 256 + cb);
    }
#pragma unroll
    for (int fm = 0; fm < 4; ++fm)
#pragma unroll
      for (int fn = 0; fn < 4; ++fn)
        acc[fm][fn] = __builtin_amdgcn_mfma_f32_16x16x32_bf16(af[fm], bf[fn], acc[fm][fn], 0, 0, 0);
  }
  // per-lane bias (4 columns, reused over fm and b)
  float bb[4];
#pragma unroll
  for (int fn = 0; fn < 4; ++fn) bb[fn] = bias[col0 + wn * 64 + fn * 16 + (l & 15)];
  // stage acc+bias (f16) into As, swizzled
  __syncthreads();
#pragma unroll
  for (int fm = 0; fm < 4; ++fm) {
    int rloc = wm * 64 + fm * 16 + ((l >> 4) << 2);
#pragma unroll
    for (int fn = 0; fn < 4; ++fn) {
      int cbyte = (wn * 64 + fn * 16 + (l & 15)) * 2;
#pragma unroll
      for (int b = 0; b < 4; ++b) {
        int r = rloc + b;
        *(ushort*)((char*)As + r * 256 + (cbyte ^ ((r & 7) << 4))) = f2h(acc[fm][fn][b] + bb[fn]);
      }
    }
  }
  __syncthreads();
  const bool isf16 = (col0 < 1024) || (col0 >= 3072);
#pragma unroll
  for (int it = 0; it < 8; ++it) {
    int idx = it * 256 + tid;
    int r = idx >> 4, cb16 = (idx & 15) << 4;
    int gr = row0 + r;
    if (gr >= M) continue;
    short8 v = *(const short8*)((const char*)As + r * 256 + (cb16 ^ ((r & 7) << 4)));
    int co = cb16 >> 1;  // col offset within 128, multiple of 8
    if (isf16) {
      int qc0 = ((col0 < 1024) ? col0 : (col0 - 2048)) + co;
      *(short8*)(qt + (size_t)gr * 1536 + qc0) = v;   // bias already in
    } else {
      float f[8];
#pragma unroll
      for (int j = 0; j < 8; ++j) f[j] = h2f((ushort)v[j]);
      unsigned w0 = 0, w1 = 0;
      w0 = enc2<false>(f[0], f[1], w0);
      w0 = enc2<true>(f[2], f[3], w0);
      w1 = enc2<false>(f[4], f[5], w1);
      w1 = enc2<true>(f[6], f[7], w1);
      uint2 st; st.x = w0; st.y = w1;
      *(uint2*)(kv8 + (size_t)gr * 2048 + (col0 - 1024) + co) = st;
    }
  }
}

// ------- fused output GEMM + GraphNorm partial sums ----------------
__global__ __launch_bounds__(256) void k_gemm_out(
    const ushort* __restrict__ s_b, const ushort* __restrict__ xin,
    const ushort* __restrict__ W2t, const ushort* __restrict__ Wsk,
    const float* __restrict__ bsk, const float* __restrict__ mbuf,
    const int* __restrict__ batch, const int* __restrict__ bptr,
    float* __restrict__ gs, float* __restrict__ gs2,
    float* __restrict__ Cf, int M) {
  __shared__ float fsm[128 * 128];          // 64 KB: ushort staging (As|Bs) then f32 tile
  ushort* As = (ushort*)fsm;                // first 32 KB
  ushort* Bs = (ushort*)fsm + 128 * 128;    // second 32 KB
  const int tid = threadIdx.x;
  const int l = tid & 63, w = tid >> 6;
  const int wm = w & 1, wn = w >> 1;
  const int row0 = blockIdx.y * 128;
  f32x4 acc[4][4] = {};
  for (int kt = 0; kt < 5; ++kt) {
    if (kt) __syncthreads();
    const char* Ab; const char* Bb; size_t arb, brb; int ko;
    if (kt < 4) { Ab = (const char*)s_b; arb = 1024; Bb = (const char*)W2t; brb = 1024; ko = kt * 256; }
    else        { Ab = (const char*)xin; arb = 256;  Bb = (const char*)Wsk; brb = 256;  ko = 0; }
#pragma unroll
    for (int i = 0; i < 8; ++i) {
      int idx = i * 256 + tid;
      int r = idx >> 4, cb = (idx & 15) << 4;
      int scb = cb ^ ((r & 7) << 4);
      GLDS(Ab + (size_t)(row0 + r) * arb + ko + scb, (char*)As + idx * 16);
      GLDS(Bb + (size_t)r * brb + ko + scb, (char*)Bs + idx * 16);
    }
    __syncthreads();
#pragma unroll
    for (int kk = 0; kk < 4; ++kk) {
      short8 af[4], bf[4];
#pragma unroll
      for (int fm = 0; fm < 4; ++fm) {
        int r = wm * 64 + fm * 16 + (l & 15);
        int cb = (kk * 64 + ((l >> 4) << 4)) ^ ((r & 7) << 4);
        af[fm] = *(const short8*)((const char*)As + r * 256 + cb);
      }
#pragma unroll
      for (int fn = 0; fn < 4; ++fn) {
        int r = wn * 64 + fn * 16 + (l & 15);
        int cb = (kk * 64 + ((l >> 4) << 4)) ^ ((r & 7) << 4);
        bf[fn] = *(const short8*)((const char*)Bs + r * 256 + cb);
      }
#pragma unroll
      for (int fm = 0; fm < 4; ++fm)
#pragma unroll
        for (int fn = 0; fn < 4; ++fn)
          acc[fm][fn] = __builtin_amdgcn_mfma_f32_16x16x32_bf16(af[fm], bf[fn], acc[fm][fn], 0, 0, 0);
    }
  }
  __syncthreads();  // all LDS reads done before tile overwrite
#pragma unroll
  for (int fm = 0; fm < 4; ++fm) {
    int rloc0 = wm * 64 + fm * 16 + ((l >> 4) << 2);
#pragma unroll
    for (int fn = 0; fn < 4; ++fn) {
      int col = wn * 64 + fn * 16 + (l & 15);
      float bb = bsk[col];
#pragma unroll
      for (int b = 0; b < 4; ++b) {
        int rloc = rloc0 + b;
        int rr = row0 + rloc;
        float val = 0.f;
        if (rr < M) {
          val = acc[fm][fn][b] + bb + mbuf[(size_t)rr * 128 + col];
          Cf[(size_t)rr * 128 + col] = val;
        }
        fsm[rloc * 128 + col] = val;
      }
    }
  }
  __syncthreads();
  // GraphNorm partial sums per batch segment in this row block
  const int c = tid & 127, half = tid >> 7;
  const int lastr = min(row0 + 127, M - 1);
  const int bmin = batch[row0 < M ? row0 : M - 1];
  const int bmax = batch[lastr];
  for (int b = bmin; b <= bmax; ++b) {
    int rlo = max(bptr[b], row0) - row0;
    int rhi = min(bptr[b + 1], min(row0 + 128, M)) - row0;
    float s = 0.f, s2 = 0.f;
    for (int r = rlo + half; r < rhi; r += 2) {
      float v = fsm[r * 128 + c];
      s += v; s2 += v * v;
    }
    if (rhi > rlo) {
      atomicAdd(&gs[b * 128 + c], s);
      atomicAdd(&gs2[b * 128 + c], s2);
    }
  }
}

// ---------------- weight prep: ALL weight transforms in ONE dispatch ----------------
struct WtPrep { const float* W[8]; ushort* O[8]; int Nc[8]; };
struct PrepPtrs {
  const float* Wq[2]; const float* We[2]; ushort* Mt[2];
  const float* bq[2]; const float* bk[2]; const float* bv[2];
  ushort* W2t[2]; float* biasAll[2];
};

// blocks [0,1024): wt transpose; [1024,1152): mwt; [1152,1692): w2t+bias
__global__ __launch_bounds__(256) void k_prep(WtPrep WP, PrepPtrs PP) {
  __shared__ float smem[64 * 129 + 16 * 129];   // 41.3 KB arena (max of branches)
  const int bid = blockIdx.x;
  const int t = threadIdx.x;
  if (bid < 1024) {
    // ---- wt transpose: z = bid>>7, by = (bid&127)>>5, bx = bid&31 ----
    const int z = bid >> 7;
    const int by = (bid & 127) >> 5, bx = bid & 31;
    const int Nc = WP.Nc[z];
    if (bx * 32 >= Nc) return;
    const float* __restrict__ W = WP.W[z];
    ushort* __restrict__ Wt = WP.O[z];
    float (*tile)[33] = (float (*)[33])smem;
    const int lx = t & 31, ly = t >> 5;
#pragma unroll
    for (int i = 0; i < 4; ++i)
      tile[ly + i * 8][lx] = W[(by * 32 + ly + i * 8) * Nc + bx * 32 + lx];
    __syncthreads();
#pragma unroll
    for (int i = 0; i < 4; ++i)
      Wt[(size_t)(bx * 32 + ly + i * 8) * 128 + by * 32 + lx] = f2b(tile[lx][ly + i * 8]);
  } else if (bid < 1152) {
    // ---- mwt: j in [0,128): L = j>>6, x = j&63, h = x>>3, pt = x&7 ----
    const int j = bid - 1024;
    const int L = j >> 6, xx = j & 63;
    const int h = xx >> 3, pt = xx & 7;
    const float* __restrict__ Wq = PP.Wq[L];
    const float* __restrict__ We = PP.We[L];
    ushort* __restrict__ Mt = PP.Mt[L];
    float (*Wes)[129] = (float (*)[129])smem;
    float (*Wqs)[129] = (float (*)[129])(smem + 64 * 129);
#pragma unroll
    for (int i = 0; i < 32; ++i) {
      int idx = i * 256 + t;
      Wes[idx >> 7][idx & 127] = We[(idx >> 7) * 1024 + h * 128 + (idx & 127)];
    }
#pragma unroll
    for (int i = 0; i < 8; ++i) {
      int idx = i * 256 + t;
      Wqs[idx >> 7][idx & 127] = Wq[(pt * 16 + (idx >> 7)) * 1024 + h * 128 + (idx & 127)];
    }
    __syncthreads();
#pragma unroll
    for (int i = 0; i < 4; ++i) {
      int o = i * 256 + t;
      int d = o & 63, pp = o >> 6;
      float s = 0.f;
#pragma unroll 8
      for (int c = 0; c < 128; ++c) s += Wqs[pp][c] * Wes[d][c];
      Mt[(size_t)(h * 64 + d) * 128 + pt * 16 + pp] = f2b(s);
    }
  } else {
    // ---- w2t + biasAll: j in [0,540): L = j/270, bx = j%270 ----
    const int j = bid - 1152;
    const int L = j / 270, bx = j % 270;
    int o = bx * 256 + t;
    if (o < 128 * 512) {
      int c = o >> 9, hd = o & 511;
      int hh = hd >> 6, d = hd & 63;
      PP.W2t[L][o] = f2b(PP.We[L][d * 1024 + hh * 128 + c] * 0.125f);
    } else {
      int o2 = o - 128 * 512;
      if (o2 >= 3584) return;
      if (o2 < 1024) PP.biasAll[L][o2] = PP.bq[L][o2];
      else if (o2 < 2048) PP.biasAll[L][o2] = PP.bk[L][o2 - 1024];
      else if (o2 < 3072) PP.biasAll[L][o2] = PP.bv[L][o2 - 2048];
      else {
        int hd = o2 - 3072;
        int h = hd >> 6, d = hd & 63;
        float s = 0.f;
        for (int c = 0; c < 128; ++c) s += PP.bq[L][h * 128 + c] * PP.We[L][d * 1024 + h * 128 + c];
        PP.biasAll[L][o2] = s;
      }
    }
  }
}

// ---------------- CSR build over dst (+ batch boundaries merged) ----------------
__global__ void k_histo_bptr(const int* __restrict__ dst, int* __restrict__ cnt,
                             const int* __restrict__ batch, int* __restrict__ bptr,
                             int nb_histo) {
  if ((int)blockIdx.x < nb_histo) {
    int e = blockIdx.x * 256 + threadIdx.x;
    if (e < NE) atomicAdd(&cnt[dst[e]], 1);
  } else {
    int b = threadIdx.x;
    if (b > NB) return;
    int lo = 0, hi = NN;
    while (lo < hi) { int mid = (lo + hi) >> 1; if (batch[mid] < b) lo = mid + 1; else hi = mid; }
    bptr[b] = lo;
  }
}

// merged scan + LPT counting sort (single block, 256 threads)
__global__ __launch_bounds__(256) void k_scan_sort(const int* __restrict__ cnt,
                                                   int* __restrict__ ptr,
                                                   int* __restrict__ order) {
  __shared__ int tsum[256];
  __shared__ int hist[256];
  __shared__ int offs[256];
  __shared__ int fill[256];
  __shared__ int sc[256];
  const int t = threadIdx.x;
  const int base = t * 40;
  int s = 0;
  for (int i = 0; i < 40; ++i) { int idx = base + i; if (idx < NN) s += cnt[idx]; }
  tsum[t] = s;
  hist[t] = 0;
  __syncthreads();
  for (int off = 1; off < 256; off <<= 1) {
    int v = (t >= off) ? tsum[t - off] : 0;
    __syncthreads();
    tsum[t] += v;
    __syncthreads();
  }
  int run = (t == 0) ? 0 : tsum[t - 1];
  for (int i = 0; i < 40; ++i) {
    int idx = base + i;
    if (idx < NN) { ptr[idx] = run; run += cnt[idx]; }
  }
  if (t == 255) ptr[NN] = tsum[255];
  for (int n = t; n < NN; n += 256) {
    int d = min(cnt[n], 255);
    atomicAdd(&hist[d], 1);
  }
  __syncthreads();
  const int rd = 255 - t;
  int v = hist[rd];
  sc[t] = v;
  __syncthreads();
  for (int off = 1; off < 256; off <<= 1) {
    int u = (t >= off) ? sc[t - off] : 0;
    __syncthreads();
    sc[t] += u;
    __syncthreads();
  }
  offs[rd] = sc[t] - v;
  fill[rd] = 0;
  __syncthreads();
  for (int n = t; n < NN; n += 256) {
    int d = min(cnt[n], 255);
    int pos = offs[d] + atomicAdd(&fill[d], 1);
    order[pos] = n;
  }
}

// countdown scatter: cnt[d] holds degree after histo; no second memset needed
__global__ void k_scatter(const int* __restrict__ dst, const int* __restrict__ ptr,
                          int* __restrict__ cnt, int* __restrict__ eid) {
  int e = blockIdx.x * 256 + threadIdx.x;
  if (e < NE) {
    int d = dst[e];
    int pos = ptr[d] + atomicSub(&cnt[d], 1) - 1;
    eid[pos] = e;
  }
}

// merged: permute attr + src into CSR order, x f32->bf16, zero GN stat buffers
__global__ void k_permattr_cvt(const int* __restrict__ eid, const int* __restrict__ src,
                               const float* __restrict__ attr, int* __restrict__ src_p,
                               ushort* __restrict__ attr_p,
                               const float* __restrict__ x, ushort* __restrict__ xb,
                               float* __restrict__ gsAll) {
  int i = blockIdx.x * 256 + threadIdx.x;
  if (i < NE * 16) {
    int idx = i >> 4, part = i & 15;
    int e = eid[idx];
    if (part == 0) src_p[idx] = src[e];
    float4 v = *(const float4*)(attr + (size_t)e * 64 + part * 4);
    ushort4 o;
    o.x = f2h(v.x); o.y = f2h(v.y); o.z = f2h(v.z); o.w = f2h(v.w);
    *(ushort4*)(attr_p + (size_t)idx * 64 + part * 4) = o;
  } else if (i < NE * 16 + NN * 128 / 4) {
    int j = i - NE * 16;
    float4 v = *(const float4*)(x + j * 4);
    ushort4 o;
    o.x = f2b(v.x); o.y = f2b(v.y); o.z = f2b(v.z); o.w = f2b(v.w);
    *(ushort4*)(xb + j * 4) = o;
  } else {
    int j = i - NE * 16 - NN * 128 / 4;
    if (j < 2 * 2 * NB * 128) gsAll[j] = 0.f;
  }
}

// ---------------- fused attention: 4 independent waves per block (LPT), fp8 k/v ----
// NOTE: no min-waves clamp (R9 spill); 1-deep prefetch only (R11 VGPR cliff).
__global__ __launch_bounds__(256) void k_fused(
    const ushort* __restrict__ qt, const unsigned char* __restrict__ kv8,
    const ushort* __restrict__ attr_p, const int* __restrict__ src_p,
    const int* __restrict__ ptr, const int* __restrict__ order,
    float* __restrict__ mbuf, ushort* __restrict__ s_b) {
  const int slot = blockIdx.x * 4 + (threadIdx.x >> 6);
  if (slot >= NN) return;
  const int n = order[slot];
  const int l = threadIdx.x & 63;
  const int i = l & 7;
  float qf[16];
  {
    H8 q0, q1;
    const ushort* qr = qt + (size_t)n * 1536 + l * 16;
    q0.s = *(const short8*)qr;
    q1.s = *(const short8*)(qr + 8);
#pragma unroll
    for (int j = 0; j < 8; ++j) { qf[j] = h2f((ushort)q0.s[j]); qf[8 + j] = h2f((ushort)q1.s[j]); }
  }
  H8 tv;
  tv.s = *(const short8*)(qt + (size_t)n * 1536 + 1024 + l * 8);
  const int beg = ptr[n], end = ptr[n + 1];
  float m = -1e30f, den = 0.f;
  float acc[16] = {};
  float sa[8] = {};
  uint4 kw, vw; H8 av;
  if (beg < end) {
    int s0 = src_p[beg];
    const unsigned char* kr = kv8 + (size_t)s0 * 2048 + l * 16;
    kw = *(const uint4*)kr;
    vw = *(const uint4*)(kr + 1024);
    av.s = *(const short8*)(attr_p + (size_t)beg * 64 + i * 8);
  }
  for (int idx = beg; idx < end; ++idx) {
    uint4 ckw = kw, cvw = vw; H8 cav = av;
    int nidx = (idx + 1 < end) ? idx + 1 : idx;
    int ns = src_p[nidx];
    const unsigned char* kr = kv8 + (size_t)ns * 2048 + l * 16;
    kw = *(const uint4*)kr;
    vw = *(const uint4*)(kr + 1024);
    av.s = *(const short8*)(attr_p + (size_t)nidx * 64 + i * 8);
    float p = 0.f;
    {
      const unsigned* kws = (const unsigned*)&ckw;
#pragma unroll
      for (int j = 0; j < 4; ++j) {
        f32x2 lo = dec2<false>(kws[j]), hi = dec2<true>(kws[j]);
        p += qf[4 * j] * lo[0] + qf[4 * j + 1] * lo[1]
           + qf[4 * j + 2] * hi[0] + qf[4 * j + 3] * hi[1];
      }
    }
#pragma unroll
    for (int j = 0; j < 4; ++j) p = FDOT2(tv.h[j], cav.h[j], p);
    p += __shfl_xor(p, 1, 64);
    p += __shfl_xor(p, 2, 64);
    p += __shfl_xor(p, 4, 64);
    p *= 0.12751593061420927f;  // (1/sqrt(128)) * log2(e) -> exp2 domain
    float mn = fmaxf(m, p);
    float r = exp2f(m - mn);
    float ex = exp2f(p - mn);
    den = den * r + ex;
    {
      const unsigned* vws = (const unsigned*)&cvw;
#pragma unroll
      for (int j = 0; j < 4; ++j) {
        f32x2 lo = dec2<false>(vws[j]), hi = dec2<true>(vws[j]);
        acc[4 * j]     = acc[4 * j]     * r + ex * lo[0];
        acc[4 * j + 1] = acc[4 * j + 1] * r + ex * lo[1];
        acc[4 * j + 2] = acc[4 * j + 2] * r + ex * hi[0];
        acc[4 * j + 3] = acc[4 * j + 3] * r + ex * hi[1];
      }
    }
#pragma unroll
    for (int j = 0; j < 4; ++j) {
      sa[2 * j]     = sa[2 * j]     * r + ex * (float)cav.h[j][0];
      sa[2 * j + 1] = sa[2 * j + 1] * r + ex * (float)cav.h[j][1];
    }
    m = mn;
  }
  const float invd = den > 0.f ? 1.f / den : 0.f;
  short8 sb;
#pragma unroll
  for (int j = 0; j < 8; ++j) sb[j] = (short)f2b(sa[j] * invd);
  *(short8*)(s_b + (size_t)n * 512 + l * 8) = sb;
#pragma unroll
  for (int j = 0; j < 16; ++j) {
    float a = acc[j] * invd;
    a += __shfl_xor(a, 8, 64);
    a += __shfl_xor(a, 16, 64);
    a += __shfl_xor(a, 32, 64);
    acc[j] = a;
  }
  if (l < 8) {  // h==0 lanes, i==l
    float* mb = mbuf + (size_t)n * 128 + l * 16;
#pragma unroll
    for (int j = 0; j < 16; j += 4) {
      float4 o = make_float4(acc[j] * 0.125f, acc[j + 1] * 0.125f,
                             acc[j + 2] * 0.125f, acc[j + 3] * 0.125f);
      *(float4*)(mb + j) = o;
    }
  }
}

// ---------------- GraphNorm apply (stats precomputed by k_gemm_out) ----------------
__global__ void k_gn_apply(const float* __restrict__ x, const int* __restrict__ batch,
                           const int* __restrict__ bptr,
                           const float* __restrict__ gs, const float* __restrict__ gs2,
                           const float* __restrict__ ms, const float* __restrict__ wgt,
                           const float* __restrict__ gnb,
                           float* __restrict__ fout, ushort* __restrict__ bout) {
  int i = blockIdx.x * 256 + threadIdx.x;
  int n = i >> 7, c = i & 127;
  int b = batch[n];
  float cnt = fmaxf((float)(bptr[b + 1] - bptr[b]), 1.f);
  float mean = gs[b * 128 + c] / cnt;
  float mm = mean * ms[c];
  float var = gs2[b * 128 + c] / cnt - 2.f * mm * mean + mm * mm;
  float o = (x[i] - mm) * rsqrtf(var + 1e-5f) * wgt[c] + gnb[c];
  o = o > 0.f ? o : 0.01f * o;
  if (fout) fout[i] = o;
  if (bout) bout[i] = f2b(o);
}

extern "C" void kernel_launch(void* const* d_in, const int* in_sizes, int n_in,
                              void* d_out, int out_size, void* d_ws, size_t ws_size,
                              hipStream_t stream) {
  const float* x     = (const float*)d_in[0];
  const int*   index = (const int*)d_in[1];
  const float* attr  = (const float*)d_in[2];
  const int*   batch = (const int*)d_in[3];
  const int* srcArr = index;
  const int* dstArr = index + NE;

  char* p = (char*)d_ws;
  auto take = [&](size_t bytes) {
    char* r = p;
    p += (bytes + 255) & ~(size_t)255;
    return (void*)r;
  };
  ushort* qt_b   = (ushort*)take((size_t)NN * 1536 * 2);   // f16 [q|t]
  unsigned char* kv8 = (unsigned char*)take((size_t)NN * 2048);  // fp8 [k|v]
  ushort* s_b    = (ushort*)take((size_t)NN * 512 * 2);    // bf16
  float*  mbuf   = (float*)take((size_t)NN * 128 * 4);
  float*  hbuf   = (float*)take((size_t)NN * 128 * 4);
  ushort* xb     = (ushort*)take((size_t)NN * 128 * 2);    // bf16
  ushort* x2b    = (ushort*)take((size_t)NN * 128 * 2);    // bf16
  ushort* attr_p = (ushort*)take((size_t)NE * 64 * 2);     // f16, CSR order
  int*    src_p  = (int*)take((size_t)NE * 4);
  float*  gsAll  = (float*)take((size_t)2 * 2 * NB * 128 * 4);  // per-layer gs|gs2
  int* csr_ptr   = (int*)take((size_t)(NN + 1) * 4);
  int* csr_cnt   = (int*)take((size_t)NN * 4);
  int* csr_eid   = (int*)take((size_t)NE * 4);
  int* nodeorder = (int*)take((size_t)NN * 4);
  int* bptrd     = (int*)take((size_t)(NB + 1) * 4);
  ushort* WtAll[2]; ushort* Wtsk[2]; ushort* W2t[2];
  float* biasAll[2];
  for (int L = 0; L < 2; ++L) {
    WtAll[L]   = (ushort*)take((size_t)3584 * 128 * 2);  // [q|k|v|t] rows, bf16
    Wtsk[L]    = (ushort*)take((size_t)128 * 128 * 2);
    W2t[L]     = (ushort*)take((size_t)128 * 512 * 2);
    biasAll[L] = (float*)take((size_t)3584 * 4);
  }

  // ---- CSR over dst + LPT order + batch boundaries + conversions ----
  const int nb_histo = (NE + 255) / 256;
  hipMemsetAsync(csr_cnt, 0, NN * 4, stream);
  k_histo_bptr<<<nb_histo + 1, 256, 0, stream>>>(dstArr, csr_cnt, batch, bptrd, nb_histo);
  k_scan_sort<<<1, 256, 0, stream>>>(csr_cnt, csr_ptr, nodeorder);
  k_scatter<<<nb_histo, 256, 0, stream>>>(dstArr, csr_ptr, csr_cnt, csr_eid);
  k_permattr_cvt<<<(NE * 16 + NN * 128 / 4 + 2 * 2 * NB * 128 + 255) / 256, 256, 0, stream>>>(
      csr_eid, srcArr, attr, src_p, attr_p, x, xb, gsAll);

  // ---- weight prep: single dispatch ----
  WtPrep WP;
  PrepPtrs PP;
  for (int L = 0; L < 2; ++L) {
    const float* Wq  = (const float*)d_in[4 + L * 12 + 0];
    const float* bq  = (const float*)d_in[4 + L * 12 + 1];
    const float* Wk  = (const float*)d_in[4 + L * 12 + 2];
    const float* bk  = (const float*)d_in[4 + L * 12 + 3];
    const float* Wv  = (const float*)d_in[4 + L * 12 + 4];
    const float* bv  = (const float*)d_in[4 + L * 12 + 5];
    const float* We  = (const float*)d_in[4 + L * 12 + 6];
    const float* Wsk = (const float*)d_in[4 + L * 12 + 7];
    WP.W[L * 4 + 0] = Wq;  WP.O[L * 4 + 0] = WtAll[L];                      WP.Nc[L * 4 + 0] = 1024;
    WP.W[L * 4 + 1] = Wk;  WP.O[L * 4 + 1] = WtAll[L] + (size_t)1024 * 128; WP.Nc[L * 4 + 1] = 1024;
    WP.W[L * 4 + 2] = Wv;  WP.O[L * 4 + 2] = WtAll[L] + (size_t)2048 * 128; WP.Nc[L * 4 + 2] = 1024;
    WP.W[L * 4 + 3] = Wsk; WP.O[L * 4 + 3] = Wtsk[L];                       WP.Nc[L * 4 + 3] = 128;
    PP.Wq[L] = Wq; PP.We[L] = We; PP.Mt[L] = WtAll[L] + (size_t)3072 * 128;
    PP.bq[L] = bq; PP.bk[L] = bk; PP.bv[L] = bv;
    PP.W2t[L] = W2t[L]; PP.biasAll[L] = biasAll[L];
  }
  k_prep<<<1692, 256, 0, stream>>>(WP, PP);

  const int MT = (NN + 127) / 128;  // 79 row tiles
  for (int L = 0; L < 2; ++L) {
    const float* bsk = (const float*)d_in[4 + L * 12 + 8];
    const float* gnw = (const float*)d_in[4 + L * 12 + 9];
    const float* gnb = (const float*)d_in[4 + L * 12 + 10];
    const float* gnm = (const float*)d_in[4 + L * 12 + 11];
    const ushort* Ain = (L == 0) ? xb : x2b;
    float* gs  = gsAll + (size_t)L * 2 * NB * 128;
    float* gs2 = gs + NB * 128;

    k_gemm_qkvt<<<dim3(28, MT), 256, 0, stream>>>(Ain, WtAll[L], biasAll[L], qt_b, kv8, NN);
    k_fused<<<(NN + 3) / 4, 256, 0, stream>>>(qt_b, kv8, attr_p, src_p, csr_ptr, nodeorder, mbuf, s_b);
    k_gemm_out<<<dim3(1, MT), 256, 0, stream>>>(
        s_b, Ain, W2t[L], Wtsk[L], bsk, mbuf, batch, bptrd, gs, gs2, hbuf, NN);
    k_gn_apply<<<NN * 128 / 256, 256, 0, stream>>>(
        hbuf, batch, bptrd, gs, gs2, gnm, gnw, gnb,
        (L == 0) ? (float*)nullptr : (float*)d_out,
        (L == 0) ? x2b : (ushort*)nullptr);
  }
}